// Round 10
// baseline (513.958 us; speedup 1.0000x reference)
//
#include <hip/hip_runtime.h>
#include <hip/hip_bf16.h>

#define NCN 10000   // computation nodes
#define ECN 120000  // computation edges
#define NHH 256     // hidden
#define CEE 16      // cedge feat dim
#define GCN 100     // cgroups
#define GSZ 100     // nodes per cgroup
#define NTT 16      // topo nodes
#define ETT 64      // topo edges
#define TGG 8       // tgroups
#define OPEE 4
#define CFF 64
#define TFF 32
#define TEE 16
#define GPB 16      // dst nodes per block in GEMM kernels (weight-load amortization)
#define HFW 272     // hf row width (256 + 16 eagg, eagg tail pre-baked)
#define HFW0 88     // layer-0 hf row width (64 cf + 4 ope + s_on + pad + 16 eaggR)

// ---------- static device scratch (no d_ws dependency) ----------
__device__ int   g_indeg[NCN];
__device__ int   g_outdeg[NCN];
__device__ int   g_cursor[NCN];
__device__ int   g_off[NCN+1];
__device__ int   g_eid[ECN];
__device__ int   g_srcarr[ECN];
__device__ float g_onorm[NCN];
__device__ float g_inorm[NCN];
__device__ float g_eaggR[NCN*CEE];
__device__ float g_tx0[NTT*NHH];
__device__ float g_tx1[NTT*NHH];
__device__ float g_v0p[TGG*NHH];
__device__ float g_v0[NHH];
__device__ float g_x0[(size_t)NCN*NHH];   // xn (normalized state) / final raw
__device__ float g_x1[(size_t)NCN*NHH];
__device__ float g_hf [(size_t)NCN*HFW];  // recurrent gather rows; [256:272] = eagg (invariant)
__device__ float g_hf0[(size_t)NCN*HFW0]; // layer-0 gather rows
__device__ float g_cembp[4*GCN*NHH];

__device__ __forceinline__ int clampi(int v,int lo,int hi){ return v<lo?lo:(v>hi?hi:v); }

__global__ __launch_bounds__(256) void k_badsize(float* out, int n, float code){
    int i = blockIdx.x*256 + threadIdx.x;
    if (i < n) out[i] = code;
}

// ---------------- graph prep ----------------
__global__ __launch_bounds__(256) void k_zero3(){
    int i = blockIdx.x*256 + threadIdx.x;
    if (i < NCN){ g_indeg[i]=0; g_outdeg[i]=0; g_cursor[i]=0; }
}

__global__ __launch_bounds__(256) void k_degrees(const int* __restrict__ src, const int* __restrict__ dst){
    int e = blockIdx.x*256 + threadIdx.x;
    if (e < ECN){
        atomicAdd(&g_outdeg[clampi(src[e],0,NCN-1)],1);
        atomicAdd(&g_indeg [clampi(dst[e],0,NCN-1)],1);
    }
}

__global__ __launch_bounds__(256) void k_norms(){
    int i = blockIdx.x*256 + threadIdx.x;
    if (i < NCN){
        g_onorm[i] = rsqrtf((float)max(g_outdeg[i],1));
        g_inorm[i] = rsqrtf((float)max(g_indeg[i],1));
    }
}

__global__ __launch_bounds__(1024) void k_scan(){
    __shared__ int cs[1024];
    const int CH = (NCN + 1023)/1024;
    int t = threadIdx.x;
    int base = t*CH;
    int s = 0;
    for (int j=0;j<CH;j++){ int idx=base+j; if (idx<NCN) s += g_indeg[idx]; }
    cs[t] = s; __syncthreads();
    for (int ofs=1; ofs<1024; ofs<<=1){
        int v = (t>=ofs) ? cs[t-ofs] : 0;
        __syncthreads();
        cs[t] += v;
        __syncthreads();
    }
    int run = (t==0) ? 0 : cs[t-1];
    for (int j=0;j<CH;j++){
        int idx = base+j;
        if (idx <= NCN) g_off[idx] = run;
        if (idx < NCN) run += g_indeg[idx];
    }
}

__global__ __launch_bounds__(256) void k_scatter(const int* __restrict__ dst){
    int e = blockIdx.x*256 + threadIdx.x;
    if (e < ECN){
        int d = clampi(dst[e],0,NCN-1);
        int pos = g_off[d] + atomicAdd(&g_cursor[d],1);
        g_eid[clampi(pos,0,ECN-1)] = e;
    }
}

// wave-per-node bitonic sort of eid (deterministic order) + srcarr fill
__global__ __launch_bounds__(256) void k_sortfill(const int* __restrict__ c_src){
    const int wv = threadIdx.x >> 6, lane = threadIdx.x & 63;
    const int d = blockIdx.x*4 + wv;
    int b = clampi(g_off[d],0,ECN), e = clampi(g_off[d+1],b,ECN);
    int deg = e - b;
    if (deg <= 64){
        int v = (lane < deg) ? g_eid[b+lane] : 0x7fffffff;
        #pragma unroll
        for (int k=2;k<=64;k<<=1){
            #pragma unroll
            for (int j=k>>1;j>0;j>>=1){
                int p = __shfl_xor(v, j, 64);
                bool takeMin = ((lane & j)==0) == ((lane & k)==0);
                v = takeMin ? min(v,p) : max(v,p);
            }
        }
        if (lane < deg){
            g_eid[b+lane] = v;
            g_srcarr[b+lane] = clampi(c_src[clampi(v,0,ECN-1)],0,NCN-1);
        }
    } else if (lane == 0){
        for (int i=b+1;i<e;i++){
            int key = g_eid[i]; int j = i-1;
            while (j>=b && g_eid[j]>key){ g_eid[j+1]=g_eid[j]; j--; }
            g_eid[j+1] = key;
        }
        for (int i=b;i<e;i++) g_srcarr[i] = clampi(c_src[clampi(g_eid[i],0,ECN-1)],0,NCN-1);
    }
}

// edge-feature aggregates: eagg -> g_hf tail (layer-invariant), eaggR -> g_eaggR (layer 0)
__global__ __launch_bounds__(256) void k_eagg(const float* __restrict__ ef){
    int d = blockIdx.x*16 + threadIdx.x/16;
    int f = threadIdx.x%16;
    if (d < NCN){
        float s=0.f, sr=0.f;
        int b=clampi(g_off[d],0,ECN), e=clampi(g_off[d+1],b,ECN);
        for (int i=b;i<e;i++){
            float v = ef[(size_t)clampi(g_eid[i],0,ECN-1)*CEE + f];
            s += v; sr += fmaxf(v,0.f);
        }
        g_hf[(size_t)d*HFW + NHH + f] = s;   // pre-baked eagg tail
        g_eaggR[(size_t)d*CEE+f] = sr;
    }
}

// ---- topo helpers ----
__device__ __forceinline__ void topo_edges_norms(
    const int* __restrict__ t_src, const int* __restrict__ t_dst,
    int* ssrc, int* sdst, int* sdeg, float* onrm, float* inrm, int t)
{
    if (t < 2*NTT) sdeg[t]=0;
    __syncthreads();
    if (t < ETT){
        int s=clampi(t_src[t],0,NTT-1), d=clampi(t_dst[t],0,NTT-1);
        ssrc[t]=s; sdst[t]=d;
        atomicAdd(&sdeg[s],1); atomicAdd(&sdeg[NTT+d],1);
    }
    __syncthreads();
    if (t < NTT){
        onrm[t]=rsqrtf((float)max(sdeg[t],1));
        inrm[t]=rsqrtf((float)max(sdeg[NTT+t],1));
    }
    __syncthreads();
}

__global__ __launch_bounds__(256) void kt_l0(
    const float* __restrict__ tfeats, const float* __restrict__ tef,
    const float* __restrict__ tW0, const float* __restrict__ tb0,
    const int* __restrict__ t_src, const int* __restrict__ t_dst)
{
    __shared__ float h[48];
    __shared__ int ssrc[ETT], sdst[ETT], sdeg[2*NTT];
    __shared__ float onrm[NTT], inrm[NTT];
    const int d = blockIdx.x, t = threadIdx.x;
    topo_edges_norms(t_src, t_dst, ssrc, sdst, sdeg, onrm, inrm, t);
    if (t < 48){
        float acc=0.f;
        for (int e=0;e<ETT;e++){
            if (sdst[e]==d){
                int s=ssrc[e];
                float v = (t<TFF) ? tfeats[s*TFF+t]*onrm[s] : tef[e*TEE+(t-TFF)];
                acc += fmaxf(v,0.f);
            }
        }
        h[t]=acc;
    }
    __syncthreads();
    float acc=0.f;
    for (int k=0;k<48;k++) acc += h[k]*tW0[k*NHH+t];
    g_tx0[d*NHH+t] = fmaxf(acc*inrm[d]+tb0[t], 0.f);
}

template<int DIR>
__global__ __launch_bounds__(256) void kt_lr(
    const float* __restrict__ tef,
    const float* __restrict__ W, const float* __restrict__ bias,
    const int* __restrict__ t_src, const int* __restrict__ t_dst, int relu_res)
{
    const float* xin  = DIR ? g_tx1 : g_tx0;
    float*       xout = DIR ? g_tx0 : g_tx1;
    __shared__ float h[NHH+TEE];
    __shared__ int ssrc[ETT], sdst[ETT], sdeg[2*NTT];
    __shared__ float onrm[NTT], inrm[NTT];
    const int d = blockIdx.x, t = threadIdx.x;
    topo_edges_norms(t_src, t_dst, ssrc, sdst, sdeg, onrm, inrm, t);
    {
        float a0=0.f, a1=0.f;
        for (int e=0;e<ETT;e++){
            if (sdst[e]==d){
                a0 += xin[ssrc[e]*NHH+t]*onrm[ssrc[e]];
                if (t<TEE) a1 += tef[e*TEE+t];
            }
        }
        h[t]=a0;
        if (t<TEE) h[NHH+t]=a1;
    }
    __syncthreads();
    float acc=0.f;
    for (int k=0;k<NHH+TEE;k++) acc += h[k]*W[(size_t)k*NHH+t];
    float val = acc*inrm[d] + bias[t];
    xout[d*NHH+t] = relu_res ? (xin[d*NHH+t]*onrm[d] + fmaxf(val,0.f)) : val;
}

__global__ __launch_bounds__(256) void k_v0(const float* __restrict__ cW0, const int* __restrict__ tgroups){
    __shared__ float srt[NHH];
    int b=blockIdx.x, c=threadIdx.x;
    int i0=clampi(tgroups[b*2+0],0,NTT-1), i1=clampi(tgroups[b*2+1],0,NTT-1);
    srt[c]=fmaxf(g_tx1[i0*NHH+c]+g_tx1[i1*NHH+c],0.f);
    __syncthreads();
    const float* Wm = cW0 + (size_t)(CFF+OPEE + b*NHH)*NHH;
    float acc=0.f;
    for (int j=0;j<NHH;j++) acc += srt[j]*Wm[(size_t)j*NHH+c];
    g_v0p[b*NHH+c]=acc;
}
__global__ __launch_bounds__(256) void k_v0r(){
    int c=threadIdx.x;
    float s=0.f;
    for (int b=0;b<TGG;b++) s+=g_v0p[b*NHH+c];
    g_v0[c]=s;
}

// ---------------- layer-0 gather: one wave per node ----------------
// hf0 row (width 88): [0:64] sum relu(cfeats)*on | [64:68] sum relu(opemb)*on | [68] s_on | [69:72]=0 | [72:88] eaggR
__global__ __launch_bounds__(256) void k_gather0(
    const int* __restrict__ ctypes,
    const float* __restrict__ cfeats, const float* __restrict__ opemb)
{
    const int wv = threadIdx.x >> 6, lane = threadIdx.x & 63;
    const int d = blockIdx.x*4 + wv;
    int b = g_off[d], e = g_off[d+1];
    float a_cf=0.f, a_op=0.f, aon=0.f;
    for (int i=b;i<e;i++){
        int s = g_srcarr[i];
        float on = g_onorm[s];
        a_cf += fmaxf(cfeats[(size_t)s*CFF+lane],0.f)*on;
        if (lane < OPEE){
            int ct = clampi(ctypes[s],0,255);
            a_op += fmaxf(opemb[ct*OPEE+lane],0.f)*on;
        }
        aon += on;
    }
    float* row = g_hf0 + (size_t)d*HFW0;
    row[lane] = a_cf;
    if (lane < OPEE)  row[CFF+lane] = a_op;
    if (lane == 4)    row[68] = aon;
    if (lane >= 5 && lane < 8) row[64+lane] = 0.f;
    if (lane >= 8 && lane < 24) row[72+(lane-8)] = g_eaggR[(size_t)d*CEE+(lane-8)];
}

// ---------------- layer-0 GEMM: no LDS, wave-uniform hf loads; writes xn0 ----------------
__global__ __launch_bounds__(256) void k_gemm0(
    const float* __restrict__ cW0, const float* __restrict__ cb0)
{
    const int d0 = blockIdx.x*GPB;
    const int col = threadIdx.x;
    const float* hfb = g_hf0 + (size_t)d0*HFW0;
    float acc[GPB];
    #pragma unroll
    for (int n=0;n<GPB;n++) acc[n]=0.f;
    for (int k4=0;k4<16;k4++){                      // cfeats rows
        float w0=cW0[(size_t)(4*k4+0)*NHH+col];
        float w1=cW0[(size_t)(4*k4+1)*NHH+col];
        float w2=cW0[(size_t)(4*k4+2)*NHH+col];
        float w3=cW0[(size_t)(4*k4+3)*NHH+col];
        #pragma unroll
        for (int n=0;n<GPB;n++){
            float4 h4 = *((const float4*)(hfb + (size_t)n*HFW0) + k4);
            acc[n] += h4.x*w0 + h4.y*w1 + h4.z*w2 + h4.w*w3;
        }
    }
    {                                                // opemb rows
        float w0=cW0[(size_t)(CFF+0)*NHH+col];
        float w1=cW0[(size_t)(CFF+1)*NHH+col];
        float w2=cW0[(size_t)(CFF+2)*NHH+col];
        float w3=cW0[(size_t)(CFF+3)*NHH+col];
        #pragma unroll
        for (int n=0;n<GPB;n++){
            float4 h4 = *((const float4*)(hfb + (size_t)n*HFW0) + 16);
            acc[n] += h4.x*w0 + h4.y*w1 + h4.z*w2 + h4.w*w3;
        }
    }
    {                                                // s_on * v0 (collapsed t_flat)
        float w=g_v0[col];
        #pragma unroll
        for (int n=0;n<GPB;n++) acc[n] += hfb[(size_t)n*HFW0+68]*w;
    }
    const float* We = cW0 + (size_t)(CFF+OPEE+TGG*NHH)*NHH;
    for (int f4=0;f4<4;f4++){                        // cedge rows
        float w0=We[(size_t)(4*f4+0)*NHH+col];
        float w1=We[(size_t)(4*f4+1)*NHH+col];
        float w2=We[(size_t)(4*f4+2)*NHH+col];
        float w3=We[(size_t)(4*f4+3)*NHH+col];
        #pragma unroll
        for (int n=0;n<GPB;n++){
            float4 h4 = *((const float4*)(hfb + (size_t)n*HFW0) + 18 + f4);
            acc[n] += h4.x*w0 + h4.y*w1 + h4.z*w2 + h4.w*w3;
        }
    }
    float bb=cb0[col];
    #pragma unroll
    for (int n=0;n<GPB;n++){
        int d=d0+n;
        g_x0[(size_t)d*NHH+col]=fmaxf(acc[n]*g_inorm[d]+bb,0.f)*g_onorm[d];
    }
}

// ---------------- recurrent gather: one wave per node, xn pre-normalized ----------------
template<int DIR>   // DIR=0: read g_x0, DIR=1: read g_x1
__global__ __launch_bounds__(256) void k_gather(){
    const float* xn = DIR ? g_x1 : g_x0;
    const int wv = threadIdx.x >> 6, lane = threadIdx.x & 63;
    const int d = blockIdx.x*4 + wv;
    int b = g_off[d], e = g_off[d+1];
    float4 a = make_float4(0.f,0.f,0.f,0.f);
    int i = b;
    for (; i+1 < e; i += 2){
        int s0 = g_srcarr[i], s1 = g_srcarr[i+1];
        float4 v0 = *((const float4*)(xn + (size_t)s0*NHH) + lane);
        float4 v1 = *((const float4*)(xn + (size_t)s1*NHH) + lane);
        a.x += v0.x; a.y += v0.y; a.z += v0.z; a.w += v0.w;
        a.x += v1.x; a.y += v1.y; a.z += v1.z; a.w += v1.w;
    }
    if (i < e){
        int s0 = g_srcarr[i];
        float4 v0 = *((const float4*)(xn + (size_t)s0*NHH) + lane);
        a.x += v0.x; a.y += v0.y; a.z += v0.z; a.w += v0.w;
    }
    *((float4*)(g_hf + (size_t)d*HFW) + lane) = a;   // eagg tail [256:272] pre-baked, untouched
}

// ---------------- recurrent GEMM: no LDS, wave-uniform hf loads ----------------
template<int DIR>   // DIR=0: residual/in g_x0 -> out g_x1; DIR=1: reverse
__global__ __launch_bounds__(256) void k_gemmr(
    const float* __restrict__ W, const float* __restrict__ bias, int relu_res)
{
    const float* xnin = DIR ? g_x1 : g_x0;
    float*       xout = DIR ? g_x0 : g_x1;
    const int d0 = blockIdx.x*GPB;
    const int col = threadIdx.x;
    const float* hfb = g_hf + (size_t)d0*HFW;
    float acc[GPB];
    #pragma unroll
    for (int n=0;n<GPB;n++) acc[n]=0.f;
    for (int k4=0;k4<HFW/4;k4++){
        float w0=W[(size_t)(4*k4+0)*NHH+col];
        float w1=W[(size_t)(4*k4+1)*NHH+col];
        float w2=W[(size_t)(4*k4+2)*NHH+col];
        float w3=W[(size_t)(4*k4+3)*NHH+col];
        #pragma unroll
        for (int n=0;n<GPB;n++){
            float4 h4 = *((const float4*)(hfb + (size_t)n*HFW) + k4);   // wave-uniform
            acc[n] += h4.x*w0 + h4.y*w1 + h4.z*w2 + h4.w*w3;
        }
    }
    float bb = bias[col];
    #pragma unroll
    for (int n=0;n<GPB;n++){
        int d = d0+n;
        float val = acc[n]*g_inorm[d]+bb;
        if (relu_res){
            float y = xnin[(size_t)d*NHH+col] + fmaxf(val,0.f);  // residual on normalized feat
            xout[(size_t)d*NHH+col] = y*g_onorm[d];              // pre-normalize for next layer
        } else {
            xout[(size_t)d*NHH+col] = val;                        // final layer: raw
        }
    }
}

// ---------------- pooling (4 deterministic partials) + heads ----------------
__global__ __launch_bounds__(256) void k_cemb(const int* __restrict__ cgroups){
    int g=blockIdx.x>>2, p=blockIdx.x&3, c=threadIdx.x;
    float s=0.f;
    for (int i=p*25;i<p*25+25;i++){
        int idx=clampi(cgroups[g*GSZ+i],0,NCN-1);
        s += g_x1[(size_t)idx*NHH+c];
    }
    g_cembp[(size_t)(p*GCN+g)*NHH+c]=s;
}

__global__ __launch_bounds__(256) void k_heads(
    const float* __restrict__ sW, const float* __restrict__ sb,
    const float* __restrict__ nW, const float* __restrict__ nb, float* __restrict__ out)
{
    __shared__ float red[256];
    __shared__ float z[9];
    int g=blockIdx.x, t=threadIdx.x;
    float e = g_cembp[(size_t)(0*GCN+g)*NHH+t] + g_cembp[(size_t)(1*GCN+g)*NHH+t]
            + g_cembp[(size_t)(2*GCN+g)*NHH+t] + g_cembp[(size_t)(3*GCN+g)*NHH+t];
    for (int j=0;j<9;j++){
        float w = (j==0) ? nW[t] : sW[t*TGG+(j-1)];
        red[t]=e*w; __syncthreads();
        for (int s=128;s>0;s>>=1){ if (t<s) red[t]+=red[t+s]; __syncthreads(); }
        if (t==0) z[j]=red[0];
        __syncthreads();
    }
    if (t==0){
        float z0 = z[0] + nb[0];
        float lsig = fminf(z0,0.f) - log1pf(expf(-fabsf(z0)));
        out[g*9+0]=lsig;
        float zz[8]; float m=-1e30f;
        for (int j=0;j<8;j++){ zz[j]=z[j+1]+sb[j]; m=fmaxf(m,zz[j]); }
        float s=0.f;
        for (int j=0;j<8;j++) s+=expf(zz[j]-m);
        float lse=m+logf(s);
        for (int j=0;j<8;j++) out[g*9+1+j]=zz[j]-lse;
    }
}

extern "C" void kernel_launch(void* const* d_in, const int* in_sizes, int n_in,
                              void* d_out, int out_size, void* d_ws, size_t ws_size,
                              hipStream_t stream) {
    const int expect[24] = {
        NCN*CFF, ECN*CEE, NTT*TFF, ETT*TEE, 256*OPEE,
        (TFF+TEE)*NHH, NHH, 3*(NHH+TEE)*NHH, 3*NHH,
        (CFF+OPEE+TGG*NHH+CEE)*NHH, NHH, 5*(NHH+CEE)*NHH, 5*NHH,
        NHH*TGG, TGG, NHH, 1,
        NCN, ECN, ECN, ETT, ETT, GCN*GSZ, TGG*2
    };
    if (n_in < 24){
        k_badsize<<<(out_size+255)/256,256,0,stream>>>((float*)d_out, out_size, 2.0e6f);
        return;
    }
    for (int i=0;i<24;i++){
        if (in_sizes[i] != expect[i]){
            k_badsize<<<(out_size+255)/256,256,0,stream>>>((float*)d_out, out_size, 1.0e6f+(float)i);
            return;
        }
    }

    const float* cfeats = (const float*)d_in[0];
    const float* cef    = (const float*)d_in[1];
    const float* tfeats = (const float*)d_in[2];
    const float* tef    = (const float*)d_in[3];
    const float* opemb  = (const float*)d_in[4];
    const float* tW0    = (const float*)d_in[5];
    const float* tb0    = (const float*)d_in[6];
    const float* tWr    = (const float*)d_in[7];
    const float* tbr    = (const float*)d_in[8];
    const float* cW0    = (const float*)d_in[9];
    const float* cb0    = (const float*)d_in[10];
    const float* cWr    = (const float*)d_in[11];
    const float* cbr    = (const float*)d_in[12];
    const float* sW     = (const float*)d_in[13];
    const float* sb     = (const float*)d_in[14];
    const float* nW     = (const float*)d_in[15];
    const float* nb     = (const float*)d_in[16];
    const int* ctypes   = (const int*)d_in[17];
    const int* c_src    = (const int*)d_in[18];
    const int* c_dst    = (const int*)d_in[19];
    const int* t_src    = (const int*)d_in[20];
    const int* t_dst    = (const int*)d_in[21];
    const int* cgroups  = (const int*)d_in[22];
    const int* tgroups  = (const int*)d_in[23];

    const int EB = (ECN+255)/256, NB = (NCN+255)/256;

    k_zero3   <<<NB, 256, 0, stream>>>();
    k_degrees <<<EB, 256, 0, stream>>>(c_src, c_dst);
    k_norms   <<<NB, 256, 0, stream>>>();
    k_scan    <<<1, 1024, 0, stream>>>();
    k_scatter <<<EB, 256, 0, stream>>>(c_dst);
    k_sortfill<<<NCN/4, 256, 0, stream>>>(c_src);
    k_eagg    <<<(NCN+15)/16, 256, 0, stream>>>(cef);

    // topo GNN
    kt_l0    <<<NTT, 256, 0, stream>>>(tfeats, tef, tW0, tb0, t_src, t_dst);
    kt_lr<0> <<<NTT, 256, 0, stream>>>(tef, tWr + (size_t)0*(NHH+TEE)*NHH, tbr + 0*NHH, t_src, t_dst, 1);
    kt_lr<1> <<<NTT, 256, 0, stream>>>(tef, tWr + (size_t)1*(NHH+TEE)*NHH, tbr + 1*NHH, t_src, t_dst, 1);
    kt_lr<0> <<<NTT, 256, 0, stream>>>(tef, tWr + (size_t)2*(NHH+TEE)*NHH, tbr + 2*NHH, t_src, t_dst, 0);
    k_v0     <<<TGG, 256, 0, stream>>>(cW0, tgroups);
    k_v0r    <<<1, 256, 0, stream>>>();

    // cGNN layer 0 (gather + GEMM), xn0 -> g_x0
    k_gather0<<<NCN/4, 256, 0, stream>>>(ctypes, cfeats, opemb);
    k_gemm0  <<<NCN/GPB, 256, 0, stream>>>(cW0, cb0);

    // 5 recurrent layers: xn ping-pong x0 -> x1 -> x0 -> x1 -> x0 -> x1 (final raw in g_x1)
    k_gather<0><<<NCN/4, 256, 0, stream>>>();
    k_gemmr <0><<<NCN/GPB, 256, 0, stream>>>(cWr + (size_t)0*(NHH+CEE)*NHH, cbr + 0*NHH, 1);
    k_gather<1><<<NCN/4, 256, 0, stream>>>();
    k_gemmr <1><<<NCN/GPB, 256, 0, stream>>>(cWr + (size_t)1*(NHH+CEE)*NHH, cbr + 1*NHH, 1);
    k_gather<0><<<NCN/4, 256, 0, stream>>>();
    k_gemmr <0><<<NCN/GPB, 256, 0, stream>>>(cWr + (size_t)2*(NHH+CEE)*NHH, cbr + 2*NHH, 1);
    k_gather<1><<<NCN/4, 256, 0, stream>>>();
    k_gemmr <1><<<NCN/GPB, 256, 0, stream>>>(cWr + (size_t)3*(NHH+CEE)*NHH, cbr + 3*NHH, 1);
    k_gather<0><<<NCN/4, 256, 0, stream>>>();
    k_gemmr <0><<<NCN/GPB, 256, 0, stream>>>(cWr + (size_t)4*(NHH+CEE)*NHH, cbr + 4*NHH, 0);

    k_cemb <<<4*GCN, 256, 0, stream>>>(cgroups);
    k_heads<<<GCN, 256, 0, stream>>>(sW, sb, nW, nb, (float*)d_out);
}

// Round 11
// 471.657 us; speedup vs baseline: 1.0897x; 1.0897x over previous
//
#include <hip/hip_runtime.h>
#include <hip/hip_bf16.h>

#define NCN 10000   // computation nodes
#define ECN 120000  // computation edges
#define NHH 256     // hidden
#define CEE 16      // cedge feat dim
#define GCN 100     // cgroups
#define GSZ 100     // nodes per cgroup
#define NTT 16      // topo nodes
#define ETT 64      // topo edges
#define TGG 8       // tgroups
#define OPEE 4
#define CFF 64
#define TFF 32
#define TEE 16
#define GPB 8       // dst nodes per block in GEMM kernels
#define HFW 272     // hf row width (256 + 16 eagg tail, pre-baked)
#define HFW0 88     // layer-0 hf row width (= 22 float4 groups)
#define NG0 22      // layer-0 weight groups
#define NGR 68      // recurrent weight groups (272/4)

// ---------- static device scratch (no d_ws dependency) ----------
__device__ int   g_indeg[NCN];
__device__ int   g_outdeg[NCN];
__device__ int   g_cursor[NCN];
__device__ int   g_off[NCN+1];
__device__ int   g_eid[ECN];
__device__ int   g_srcarr[ECN];
__device__ float g_onorm[NCN];
__device__ float g_inorm[NCN];
__device__ float g_eaggR[NCN*CEE];
__device__ float g_tx0[NTT*NHH];
__device__ float g_tx1[NTT*NHH];
__device__ float g_v0p[TGG*NHH];
__device__ float g_x0[(size_t)NCN*NHH];   // xn (normalized state)
__device__ float g_x1[(size_t)NCN*NHH];
__device__ float g_hf [((size_t)NCN+1)*HFW];   // +1 row pad (prefetch overrun)
__device__ float g_hf0[((size_t)NCN+1)*HFW0];  // +1 row pad
__device__ float g_wp [(5*NGR*NHH + NHH)*4];   // packed cWr (+pad group)
__device__ float g_wp0[(NG0*NHH + NHH)*4];     // packed cW0 groups (+pad)
__device__ float g_cembp[4*GCN*NHH];

__device__ __forceinline__ int clampi(int v,int lo,int hi){ return v<lo?lo:(v>hi?hi:v); }

__global__ __launch_bounds__(256) void k_badsize(float* out, int n, float code){
    int i = blockIdx.x*256 + threadIdx.x;
    if (i < n) out[i] = code;
}

// ---------------- weight packing (once per launch) ----------------
// g_wp[(l*NGR + k4)*NHH + col] = float4{ W[4k4+0..3][col] }
__global__ __launch_bounds__(256) void k_packwr(const float* __restrict__ cWr){
    int i = blockIdx.x*256 + threadIdx.x;             // over 5*NGR*NHH
    if (i < 5*NGR*NHH){
        int col = i & 255, k4 = (i>>8) % NGR, l = i/(NGR*NHH);
        const float* W = cWr + (size_t)l*HFW*NHH;
        float4 w;
        w.x = W[(size_t)(4*k4+0)*NHH+col];
        w.y = W[(size_t)(4*k4+1)*NHH+col];
        w.z = W[(size_t)(4*k4+2)*NHH+col];
        w.w = W[(size_t)(4*k4+3)*NHH+col];
        ((float4*)g_wp)[i] = w;
    }
}
// g_wp0 groups: 0..16 = cW0 rows 4g..4g+3 (cf+ope); 17 = v0 (written by k_v0r); 18..21 = cedge rows
__global__ __launch_bounds__(256) void k_packw0(const float* __restrict__ cW0){
    int i = blockIdx.x*256 + threadIdx.x;             // over NG0*NHH
    if (i < NG0*NHH){
        int col = i & 255, g = i >> 8;
        if (g == 17) return;                          // v0 group
        int r = (g < 17) ? 4*g : (CFF+OPEE+TGG*NHH) + 4*(g-18);
        float4 w;
        w.x = cW0[(size_t)(r+0)*NHH+col];
        w.y = cW0[(size_t)(r+1)*NHH+col];
        w.z = cW0[(size_t)(r+2)*NHH+col];
        w.w = cW0[(size_t)(r+3)*NHH+col];
        ((float4*)g_wp0)[i] = w;
    }
}

// ---------------- graph prep ----------------
__global__ __launch_bounds__(256) void k_zero3(){
    int i = blockIdx.x*256 + threadIdx.x;
    if (i < NCN){ g_indeg[i]=0; g_outdeg[i]=0; g_cursor[i]=0; }
}

__global__ __launch_bounds__(256) void k_degrees(const int* __restrict__ src, const int* __restrict__ dst){
    int e = blockIdx.x*256 + threadIdx.x;
    if (e < ECN){
        atomicAdd(&g_outdeg[clampi(src[e],0,NCN-1)],1);
        atomicAdd(&g_indeg [clampi(dst[e],0,NCN-1)],1);
    }
}

__global__ __launch_bounds__(256) void k_norms(){
    int i = blockIdx.x*256 + threadIdx.x;
    if (i < NCN){
        g_onorm[i] = rsqrtf((float)max(g_outdeg[i],1));
        g_inorm[i] = rsqrtf((float)max(g_indeg[i],1));
    }
}

__global__ __launch_bounds__(1024) void k_scan(){
    __shared__ int cs[1024];
    const int CH = (NCN + 1023)/1024;
    int t = threadIdx.x;
    int base = t*CH;
    int s = 0;
    for (int j=0;j<CH;j++){ int idx=base+j; if (idx<NCN) s += g_indeg[idx]; }
    cs[t] = s; __syncthreads();
    for (int ofs=1; ofs<1024; ofs<<=1){
        int v = (t>=ofs) ? cs[t-ofs] : 0;
        __syncthreads();
        cs[t] += v;
        __syncthreads();
    }
    int run = (t==0) ? 0 : cs[t-1];
    for (int j=0;j<CH;j++){
        int idx = base+j;
        if (idx <= NCN) g_off[idx] = run;
        if (idx < NCN) run += g_indeg[idx];
    }
}

__global__ __launch_bounds__(256) void k_scatter(const int* __restrict__ dst){
    int e = blockIdx.x*256 + threadIdx.x;
    if (e < ECN){
        int d = clampi(dst[e],0,NCN-1);
        int pos = g_off[d] + atomicAdd(&g_cursor[d],1);
        g_eid[clampi(pos,0,ECN-1)] = e;
    }
}

// wave-per-node bitonic sort of eid (deterministic order) + srcarr fill
__global__ __launch_bounds__(256) void k_sortfill(const int* __restrict__ c_src){
    const int wv = threadIdx.x >> 6, lane = threadIdx.x & 63;
    const int d = blockIdx.x*4 + wv;
    int b = clampi(g_off[d],0,ECN), e = clampi(g_off[d+1],b,ECN);
    int deg = e - b;
    if (deg <= 64){
        int v = (lane < deg) ? g_eid[b+lane] : 0x7fffffff;
        #pragma unroll
        for (int k=2;k<=64;k<<=1){
            #pragma unroll
            for (int j=k>>1;j>0;j>>=1){
                int p = __shfl_xor(v, j, 64);
                bool takeMin = ((lane & j)==0) == ((lane & k)==0);
                v = takeMin ? min(v,p) : max(v,p);
            }
        }
        if (lane < deg){
            g_eid[b+lane] = v;
            g_srcarr[b+lane] = clampi(c_src[clampi(v,0,ECN-1)],0,NCN-1);
        }
    } else if (lane == 0){
        for (int i=b+1;i<e;i++){
            int key = g_eid[i]; int j = i-1;
            while (j>=b && g_eid[j]>key){ g_eid[j+1]=g_eid[j]; j--; }
            g_eid[j+1] = key;
        }
        for (int i=b;i<e;i++) g_srcarr[i] = clampi(c_src[clampi(g_eid[i],0,ECN-1)],0,NCN-1);
    }
}

// edge-feature aggregates: eagg -> g_hf tail (layer-invariant), eaggR -> g_eaggR (layer 0)
__global__ __launch_bounds__(256) void k_eagg(const float* __restrict__ ef){
    int d = blockIdx.x*16 + threadIdx.x/16;
    int f = threadIdx.x%16;
    if (d < NCN){
        float s=0.f, sr=0.f;
        int b=clampi(g_off[d],0,ECN), e=clampi(g_off[d+1],b,ECN);
        for (int i=b;i<e;i++){
            float v = ef[(size_t)clampi(g_eid[i],0,ECN-1)*CEE + f];
            s += v; sr += fmaxf(v,0.f);
        }
        g_hf[(size_t)d*HFW + NHH + f] = s;
        g_eaggR[(size_t)d*CEE+f] = sr;
    }
}

// ---- topo helpers ----
__device__ __forceinline__ void topo_edges_norms(
    const int* __restrict__ t_src, const int* __restrict__ t_dst,
    int* ssrc, int* sdst, int* sdeg, float* onrm, float* inrm, int t)
{
    if (t < 2*NTT) sdeg[t]=0;
    __syncthreads();
    if (t < ETT){
        int s=clampi(t_src[t],0,NTT-1), d=clampi(t_dst[t],0,NTT-1);
        ssrc[t]=s; sdst[t]=d;
        atomicAdd(&sdeg[s],1); atomicAdd(&sdeg[NTT+d],1);
    }
    __syncthreads();
    if (t < NTT){
        onrm[t]=rsqrtf((float)max(sdeg[t],1));
        inrm[t]=rsqrtf((float)max(sdeg[NTT+t],1));
    }
    __syncthreads();
}

__global__ __launch_bounds__(256) void kt_l0(
    const float* __restrict__ tfeats, const float* __restrict__ tef,
    const float* __restrict__ tW0, const float* __restrict__ tb0,
    const int* __restrict__ t_src, const int* __restrict__ t_dst)
{
    __shared__ float h[48];
    __shared__ int ssrc[ETT], sdst[ETT], sdeg[2*NTT];
    __shared__ float onrm[NTT], inrm[NTT];
    const int d = blockIdx.x, t = threadIdx.x;
    topo_edges_norms(t_src, t_dst, ssrc, sdst, sdeg, onrm, inrm, t);
    if (t < 48){
        float acc=0.f;
        for (int e=0;e<ETT;e++){
            if (sdst[e]==d){
                int s=ssrc[e];
                float v = (t<TFF) ? tfeats[s*TFF+t]*onrm[s] : tef[e*TEE+(t-TFF)];
                acc += fmaxf(v,0.f);
            }
        }
        h[t]=acc;
    }
    __syncthreads();
    float acc=0.f;
    for (int k=0;k<48;k++) acc += h[k]*tW0[k*NHH+t];
    g_tx0[d*NHH+t] = fmaxf(acc*inrm[d]+tb0[t], 0.f);
}

template<int DIR>
__global__ __launch_bounds__(256) void kt_lr(
    const float* __restrict__ tef,
    const float* __restrict__ W, const float* __restrict__ bias,
    const int* __restrict__ t_src, const int* __restrict__ t_dst, int relu_res)
{
    const float* xin  = DIR ? g_tx1 : g_tx0;
    float*       xout = DIR ? g_tx0 : g_tx1;
    __shared__ float h[NHH+TEE];
    __shared__ int ssrc[ETT], sdst[ETT], sdeg[2*NTT];
    __shared__ float onrm[NTT], inrm[NTT];
    const int d = blockIdx.x, t = threadIdx.x;
    topo_edges_norms(t_src, t_dst, ssrc, sdst, sdeg, onrm, inrm, t);
    {
        float a0=0.f, a1=0.f;
        for (int e=0;e<ETT;e++){
            if (sdst[e]==d){
                a0 += xin[ssrc[e]*NHH+t]*onrm[ssrc[e]];
                if (t<TEE) a1 += tef[e*TEE+t];
            }
        }
        h[t]=a0;
        if (t<TEE) h[NHH+t]=a1;
    }
    __syncthreads();
    float acc=0.f;
    for (int k=0;k<NHH+TEE;k++) acc += h[k]*W[(size_t)k*NHH+t];
    float val = acc*inrm[d] + bias[t];
    xout[d*NHH+t] = relu_res ? (xin[d*NHH+t]*onrm[d] + fmaxf(val,0.f)) : val;
}

__global__ __launch_bounds__(256) void k_v0(const float* __restrict__ cW0, const int* __restrict__ tgroups){
    __shared__ float srt[NHH];
    int b=blockIdx.x, c=threadIdx.x;
    int i0=clampi(tgroups[b*2+0],0,NTT-1), i1=clampi(tgroups[b*2+1],0,NTT-1);
    srt[c]=fmaxf(g_tx1[i0*NHH+c]+g_tx1[i1*NHH+c],0.f);
    __syncthreads();
    const float* Wm = cW0 + (size_t)(CFF+OPEE + b*NHH)*NHH;
    float acc=0.f;
    for (int j=0;j<NHH;j++) acc += srt[j]*Wm[(size_t)j*NHH+c];
    g_v0p[b*NHH+c]=acc;
}
// v0 reduce -> wp0 group 17 as {v0,0,0,0}
__global__ __launch_bounds__(256) void k_v0r(){
    int c=threadIdx.x;
    float s=0.f;
    for (int b=0;b<TGG;b++) s+=g_v0p[b*NHH+c];
    ((float4*)g_wp0)[17*NHH+c] = make_float4(s,0.f,0.f,0.f);
}

// ---------------- layer-0 gather: one wave per node ----------------
// hf0 row (88): [0:64] sum relu(cf)*on | [64:68] sum relu(ope)*on | [68] s_on | [69:72]=0 | [72:88] eaggR
__global__ __launch_bounds__(256) void k_gather0(
    const int* __restrict__ ctypes,
    const float* __restrict__ cfeats, const float* __restrict__ opemb)
{
    const int wv = threadIdx.x >> 6, lane = threadIdx.x & 63;
    const int d = blockIdx.x*4 + wv;
    int b = g_off[d], e = g_off[d+1];
    float a_cf=0.f, a_op=0.f, aon=0.f;
    for (int i=b;i<e;i++){
        int s = g_srcarr[i];
        float on = g_onorm[s];
        a_cf += fmaxf(cfeats[(size_t)s*CFF+lane],0.f)*on;
        if (lane < OPEE){
            int ct = clampi(ctypes[s],0,255);
            a_op += fmaxf(opemb[ct*OPEE+lane],0.f)*on;
        }
        aon += on;
    }
    float* row = g_hf0 + (size_t)d*HFW0;
    row[lane] = a_cf;
    if (lane < OPEE)  row[CFF+lane] = a_op;
    if (lane == 4)    row[68] = aon;
    if (lane >= 5 && lane < 8) row[64+lane] = 0.f;
    if (lane >= 8 && lane < 24) row[72+(lane-8)] = g_eaggR[(size_t)d*CEE+(lane-8)];
}

// ---------------- layer-0 GEMM: packed weights, prefetch; writes xn0 ----------------
__global__ __launch_bounds__(256) void k_gemm0(const float* __restrict__ cb0){
    const int d0 = blockIdx.x*GPB;
    const int col = threadIdx.x;
    const float4* hfq = (const float4*)(g_hf0 + (size_t)d0*HFW0);
    const float4* wq  = (const float4*)g_wp0;
    float4 h[GPB], hn[GPB];
    float acc[GPB];
    #pragma unroll
    for (int n=0;n<GPB;n++){ acc[n]=0.f; h[n]=hfq[n*(HFW0/4)]; }
    float4 w = wq[col];
    for (int g=0; g<NG0; g++){
        float4 wn = wq[(g+1)*NHH+col];              // pad group keeps in-bounds
        #pragma unroll
        for (int n=0;n<GPB;n++) hn[n] = hfq[n*(HFW0/4) + g+1];   // pad row keeps in-bounds
        #pragma unroll
        for (int n=0;n<GPB;n++)
            acc[n] += h[n].x*w.x + h[n].y*w.y + h[n].z*w.z + h[n].w*w.w;
        w = wn;
        #pragma unroll
        for (int n=0;n<GPB;n++) h[n]=hn[n];
    }
    float bb=cb0[col];
    #pragma unroll
    for (int n=0;n<GPB;n++){
        int d=d0+n;
        g_x0[(size_t)d*NHH+col]=fmaxf(acc[n]*g_inorm[d]+bb,0.f)*g_onorm[d];
    }
}

// ---------------- recurrent gather: one wave per node, xn pre-normalized ----------------
template<int DIR>   // DIR=0: read g_x0, DIR=1: read g_x1
__global__ __launch_bounds__(256) void k_gather(){
    const float* xn = DIR ? g_x1 : g_x0;
    const int wv = threadIdx.x >> 6, lane = threadIdx.x & 63;
    const int d = blockIdx.x*4 + wv;
    int b = g_off[d], e = g_off[d+1];
    float4 a = make_float4(0.f,0.f,0.f,0.f);
    int i = b;
    for (; i+1 < e; i += 2){
        int s0 = g_srcarr[i], s1 = g_srcarr[i+1];
        float4 v0 = *((const float4*)(xn + (size_t)s0*NHH) + lane);
        float4 v1 = *((const float4*)(xn + (size_t)s1*NHH) + lane);
        a.x += v0.x; a.y += v0.y; a.z += v0.z; a.w += v0.w;
        a.x += v1.x; a.y += v1.y; a.z += v1.z; a.w += v1.w;
    }
    if (i < e){
        int s0 = g_srcarr[i];
        float4 v0 = *((const float4*)(xn + (size_t)s0*NHH) + lane);
        a.x += v0.x; a.y += v0.y; a.z += v0.z; a.w += v0.w;
    }
    *((float4*)(g_hf + (size_t)d*HFW) + lane) = a;   // eagg tail [256:272] pre-baked
}

// ---------------- recurrent GEMM: packed weights, prefetch ----------------
template<int DIR>   // DIR=0: residual/in g_x0 -> out g_x1; DIR=1: reverse
__global__ __launch_bounds__(256) void k_gemmr(
    int loff, const float* __restrict__ bias, int relu_res)
{
    const float* xnin = DIR ? g_x1 : g_x0;
    float*       xout = DIR ? g_x0 : g_x1;
    const int d0 = blockIdx.x*GPB;
    const int col = threadIdx.x;
    const float4* hfq = (const float4*)(g_hf + (size_t)d0*HFW);
    const float4* wq  = (const float4*)g_wp + (size_t)loff;
    float4 h[GPB], hn[GPB];
    float acc[GPB];
    #pragma unroll
    for (int n=0;n<GPB;n++){ acc[n]=0.f; h[n]=hfq[n*(HFW/4)]; }
    float4 w = wq[col];
    for (int k4=0; k4<NGR; k4++){
        float4 wn = wq[(k4+1)*NHH+col];             // pad group keeps in-bounds
        #pragma unroll
        for (int n=0;n<GPB;n++) hn[n] = hfq[n*(HFW/4) + k4+1];   // pad row keeps in-bounds
        #pragma unroll
        for (int n=0;n<GPB;n++)
            acc[n] += h[n].x*w.x + h[n].y*w.y + h[n].z*w.z + h[n].w*w.w;
        w = wn;
        #pragma unroll
        for (int n=0;n<GPB;n++) h[n]=hn[n];
    }
    float bb = bias[col];
    #pragma unroll
    for (int n=0;n<GPB;n++){
        int d = d0+n;
        float val = acc[n]*g_inorm[d]+bb;
        if (relu_res){
            float y = xnin[(size_t)d*NHH+col] + fmaxf(val,0.f);
            xout[(size_t)d*NHH+col] = y*g_onorm[d];
        } else {
            xout[(size_t)d*NHH+col] = val;
        }
    }
}

// ---------------- pooling (4 deterministic partials) + heads ----------------
__global__ __launch_bounds__(256) void k_cemb(const int* __restrict__ cgroups){
    int g=blockIdx.x>>2, p=blockIdx.x&3, c=threadIdx.x;
    float s=0.f;
    for (int i=p*25;i<p*25+25;i++){
        int idx=clampi(cgroups[g*GSZ+i],0,NCN-1);
        s += g_x1[(size_t)idx*NHH+c];
    }
    g_cembp[(size_t)(p*GCN+g)*NHH+c]=s;
}

__global__ __launch_bounds__(256) void k_heads(
    const float* __restrict__ sW, const float* __restrict__ sb,
    const float* __restrict__ nW, const float* __restrict__ nb, float* __restrict__ out)
{
    __shared__ float red[256];
    __shared__ float z[9];
    int g=blockIdx.x, t=threadIdx.x;
    float e = g_cembp[(size_t)(0*GCN+g)*NHH+t] + g_cembp[(size_t)(1*GCN+g)*NHH+t]
            + g_cembp[(size_t)(2*GCN+g)*NHH+t] + g_cembp[(size_t)(3*GCN+g)*NHH+t];
    for (int j=0;j<9;j++){
        float w = (j==0) ? nW[t] : sW[t*TGG+(j-1)];
        red[t]=e*w; __syncthreads();
        for (int s=128;s>0;s>>=1){ if (t<s) red[t]+=red[t+s]; __syncthreads(); }
        if (t==0) z[j]=red[0];
        __syncthreads();
    }
    if (t==0){
        float z0 = z[0] + nb[0];
        float lsig = fminf(z0,0.f) - log1pf(expf(-fabsf(z0)));
        out[g*9+0]=lsig;
        float zz[8]; float m=-1e30f;
        for (int j=0;j<8;j++){ zz[j]=z[j+1]+sb[j]; m=fmaxf(m,zz[j]); }
        float s=0.f;
        for (int j=0;j<8;j++) s+=expf(zz[j]-m);
        float lse=m+logf(s);
        for (int j=0;j<8;j++) out[g*9+1+j]=zz[j]-lse;
    }
}

extern "C" void kernel_launch(void* const* d_in, const int* in_sizes, int n_in,
                              void* d_out, int out_size, void* d_ws, size_t ws_size,
                              hipStream_t stream) {
    const int expect[24] = {
        NCN*CFF, ECN*CEE, NTT*TFF, ETT*TEE, 256*OPEE,
        (TFF+TEE)*NHH, NHH, 3*(NHH+TEE)*NHH, 3*NHH,
        (CFF+OPEE+TGG*NHH+CEE)*NHH, NHH, 5*(NHH+CEE)*NHH, 5*NHH,
        NHH*TGG, TGG, NHH, 1,
        NCN, ECN, ECN, ETT, ETT, GCN*GSZ, TGG*2
    };
    if (n_in < 24){
        k_badsize<<<(out_size+255)/256,256,0,stream>>>((float*)d_out, out_size, 2.0e6f);
        return;
    }
    for (int i=0;i<24;i++){
        if (in_sizes[i] != expect[i]){
            k_badsize<<<(out_size+255)/256,256,0,stream>>>((float*)d_out, out_size, 1.0e6f+(float)i);
            return;
        }
    }

    const float* cfeats = (const float*)d_in[0];
    const float* cef    = (const float*)d_in[1];
    const float* tfeats = (const float*)d_in[2];
    const float* tef    = (const float*)d_in[3];
    const float* opemb  = (const float*)d_in[4];
    const float* tW0    = (const float*)d_in[5];
    const float* tb0    = (const float*)d_in[6];
    const float* tWr    = (const float*)d_in[7];
    const float* tbr    = (const float*)d_in[8];
    const float* cW0    = (const float*)d_in[9];
    const float* cb0    = (const float*)d_in[10];
    const float* cWr    = (const float*)d_in[11];
    const float* cbr    = (const float*)d_in[12];
    const float* sW     = (const float*)d_in[13];
    const float* sb     = (const float*)d_in[14];
    const float* nW     = (const float*)d_in[15];
    const float* nb     = (const float*)d_in[16];
    const int* ctypes   = (const int*)d_in[17];
    const int* c_src    = (const int*)d_in[18];
    const int* c_dst    = (const int*)d_in[19];
    const int* t_src    = (const int*)d_in[20];
    const int* t_dst    = (const int*)d_in[21];
    const int* cgroups  = (const int*)d_in[22];
    const int* tgroups  = (const int*)d_in[23];

    const int EB = (ECN+255)/256, NB = (NCN+255)/256;

    k_packwr  <<<(5*NGR*NHH+255)/256, 256, 0, stream>>>(cWr);
    k_packw0  <<<(NG0*NHH+255)/256, 256, 0, stream>>>(cW0);

    k_zero3   <<<NB, 256, 0, stream>>>();
    k_degrees <<<EB, 256, 0, stream>>>(c_src, c_dst);
    k_norms   <<<NB, 256, 0, stream>>>();
    k_scan    <<<1, 1024, 0, stream>>>();
    k_scatter <<<EB, 256, 0, stream>>>(c_dst);
    k_sortfill<<<NCN/4, 256, 0, stream>>>(c_src);
    k_eagg    <<<(NCN+15)/16, 256, 0, stream>>>(cef);

    // topo GNN
    kt_l0    <<<NTT, 256, 0, stream>>>(tfeats, tef, tW0, tb0, t_src, t_dst);
    kt_lr<0> <<<NTT, 256, 0, stream>>>(tef, tWr + (size_t)0*(NHH+TEE)*NHH, tbr + 0*NHH, t_src, t_dst, 1);
    kt_lr<1> <<<NTT, 256, 0, stream>>>(tef, tWr + (size_t)1*(NHH+TEE)*NHH, tbr + 1*NHH, t_src, t_dst, 1);
    kt_lr<0> <<<NTT, 256, 0, stream>>>(tef, tWr + (size_t)2*(NHH+TEE)*NHH, tbr + 2*NHH, t_src, t_dst, 0);
    k_v0     <<<TGG, 256, 0, stream>>>(cW0, tgroups);
    k_v0r    <<<1, 256, 0, stream>>>();

    // cGNN layer 0 (gather + GEMM), xn0 -> g_x0
    k_gather0<<<NCN/4, 256, 0, stream>>>(ctypes, cfeats, opemb);
    k_gemm0  <<<NCN/GPB, 256, 0, stream>>>(cb0);

    // 5 recurrent layers: xn ping-pong x0 -> x1 -> x0 -> x1 -> x0 -> x1 (final raw in g_x1)
    k_gather<0><<<NCN/4, 256, 0, stream>>>();
    k_gemmr <0><<<NCN/GPB, 256, 0, stream>>>(0*NGR*NHH, cbr + 0*NHH, 1);
    k_gather<1><<<NCN/4, 256, 0, stream>>>();
    k_gemmr <1><<<NCN/GPB, 256, 0, stream>>>(1*NGR*NHH, cbr + 1*NHH, 1);
    k_gather<0><<<NCN/4, 256, 0, stream>>>();
    k_gemmr <0><<<NCN/GPB, 256, 0, stream>>>(2*NGR*NHH, cbr + 2*NHH, 1);
    k_gather<1><<<NCN/4, 256, 0, stream>>>();
    k_gemmr <1><<<NCN/GPB, 256, 0, stream>>>(3*NGR*NHH, cbr + 3*NHH, 1);
    k_gather<0><<<NCN/4, 256, 0, stream>>>();
    k_gemmr <0><<<NCN/GPB, 256, 0, stream>>>(4*NGR*NHH, cbr + 4*NHH, 0);

    k_cemb <<<4*GCN, 256, 0, stream>>>(cgroups);
    k_heads<<<GCN, 256, 0, stream>>>(sW, sb, nW, nb, (float*)d_out);
}

// Round 12
// 336.917 us; speedup vs baseline: 1.5255x; 1.3999x over previous
//
#include <hip/hip_runtime.h>
#include <hip/hip_bf16.h>

#define NCN 10000   // computation nodes
#define ECN 120000  // computation edges
#define NHH 256     // hidden
#define CEE 16      // cedge feat dim
#define GCN 100     // cgroups
#define GSZ 100     // nodes per cgroup
#define NTT 16      // topo nodes
#define ETT 64      // topo edges
#define TGG 8       // tgroups
#define OPEE 4
#define CFF 64
#define TFF 32
#define TEE 16
#define HFW 272     // true K (256 + 16 eagg)
#define HFB 288     // padded K for MFMA (9*32)
#define HFB0 96     // layer-0 padded K (3*32)

typedef __attribute__((ext_vector_type(8))) short bf16x8;
typedef __attribute__((ext_vector_type(4))) float f32x4;

// ---------- static device scratch (no d_ws dependency) ----------
__device__ int    g_indeg[NCN];
__device__ int    g_outdeg[NCN];
__device__ int    g_cursor[NCN];
__device__ int    g_off[NCN+1];
__device__ int    g_eid[ECN];
__device__ int    g_srcarr[ECN];
__device__ float  g_onorm[NCN];
__device__ float  g_inorm[NCN];
__device__ float  g_son[NCN];
__device__ float  g_tx0[NTT*NHH];
__device__ float  g_tx1[NTT*NHH];
__device__ float  g_v0p[TGG*NHH];
__device__ float  g_v0[NHH];
__device__ float  g_x0[(size_t)NCN*NHH];     // f32 xn state (normalized) / final raw
__device__ float  g_x1[(size_t)NCN*NHH];
__device__ ushort g_xb0[(size_t)NCN*NHH];    // bf16 mirror of xn (gather input)
__device__ ushort g_xb1[(size_t)NCN*NHH];
__device__ ushort g_hf [(size_t)NCN*HFB];    // bf16 gathered rows; [256:272]=eagg, [272:288]=0
__device__ ushort g_hf0[(size_t)NCN*HFB0];   // bf16 layer-0 rows
__device__ ushort g_wpk [5*9*16*64*8];       // cWr packed into B-fragment order
__device__ ushort g_wpk0[3*16*64*8];         // cW0 packed (k=68..71 zeroed; v0 term in f32 epilogue)
__device__ float  g_cembp[4*GCN*NHH];

__device__ __forceinline__ int clampi(int v,int lo,int hi){ return v<lo?lo:(v>hi?hi:v); }
__device__ __forceinline__ ushort f2bu(float f){ __hip_bfloat16 h=__float2bfloat16(f); return *reinterpret_cast<ushort*>(&h); }
__device__ __forceinline__ float  bu2f(ushort u){ return __uint_as_float(((unsigned)u)<<16); }

__global__ __launch_bounds__(256) void k_badsize(float* out, int n, float code){
    int i = blockIdx.x*256 + threadIdx.x;
    if (i < n) out[i] = code;
}

// ---------------- weight packing: B-fragment order (col=lane&15, k=kt*32+8*(lane>>4)+j) ----------------
__global__ __launch_bounds__(256) void k_packwr(const float* __restrict__ cWr){
    int i = blockIdx.x*256 + threadIdx.x;      // over 5*9*16*64
    if (i >= 5*9*16*64) return;
    int lane = i&63, t = i>>6;
    int ntg = t&15; t >>= 4;
    int kt = t%9, l = t/9;
    int col = ntg*16 + (lane&15);
    int kb = kt*32 + 8*(lane>>4);
    #pragma unroll
    for (int j=0;j<8;j++){
        int k = kb + j;
        float v = (k < HFW) ? cWr[(size_t)l*HFW*NHH + (size_t)k*NHH + col] : 0.f;
        g_wpk[(size_t)i*8 + j] = f2bu(v);
    }
}
__global__ __launch_bounds__(256) void k_packw0(const float* __restrict__ cW0){
    int i = blockIdx.x*256 + threadIdx.x;      // over 3*16*64
    if (i >= 3*16*64) return;
    int lane = i&63, t = i>>6;
    int ntg = t&15, kt = t>>4;
    int col = ntg*16 + (lane&15);
    int kb = kt*32 + 8*(lane>>4);
    #pragma unroll
    for (int j=0;j<8;j++){
        int k = kb + j;
        float v = 0.f;
        if (k < CFF+OPEE)            v = cW0[(size_t)k*NHH+col];
        else if (k >= 72 && k < 88)  v = cW0[(size_t)(CFF+OPEE+TGG*NHH + (k-72))*NHH + col];
        g_wpk0[(size_t)i*8 + j] = f2bu(v);
    }
}

// ---------------- graph prep ----------------
__global__ __launch_bounds__(256) void k_zero3(){
    int i = blockIdx.x*256 + threadIdx.x;
    if (i < NCN){ g_indeg[i]=0; g_outdeg[i]=0; g_cursor[i]=0; }
}

__global__ __launch_bounds__(256) void k_degrees(const int* __restrict__ src, const int* __restrict__ dst){
    int e = blockIdx.x*256 + threadIdx.x;
    if (e < ECN){
        atomicAdd(&g_outdeg[clampi(src[e],0,NCN-1)],1);
        atomicAdd(&g_indeg [clampi(dst[e],0,NCN-1)],1);
    }
}

__global__ __launch_bounds__(256) void k_norms(){
    int i = blockIdx.x*256 + threadIdx.x;
    if (i < NCN){
        g_onorm[i] = rsqrtf((float)max(g_outdeg[i],1));
        g_inorm[i] = rsqrtf((float)max(g_indeg[i],1));
    }
}

__global__ __launch_bounds__(1024) void k_scan(){
    __shared__ int cs[1024];
    const int CH = (NCN + 1023)/1024;
    int t = threadIdx.x;
    int base = t*CH;
    int s = 0;
    for (int j=0;j<CH;j++){ int idx=base+j; if (idx<NCN) s += g_indeg[idx]; }
    cs[t] = s; __syncthreads();
    for (int ofs=1; ofs<1024; ofs<<=1){
        int v = (t>=ofs) ? cs[t-ofs] : 0;
        __syncthreads();
        cs[t] += v;
        __syncthreads();
    }
    int run = (t==0) ? 0 : cs[t-1];
    for (int j=0;j<CH;j++){
        int idx = base+j;
        if (idx <= NCN) g_off[idx] = run;
        if (idx < NCN) run += g_indeg[idx];
    }
}

__global__ __launch_bounds__(256) void k_scatter(const int* __restrict__ dst){
    int e = blockIdx.x*256 + threadIdx.x;
    if (e < ECN){
        int d = clampi(dst[e],0,NCN-1);
        int pos = g_off[d] + atomicAdd(&g_cursor[d],1);
        g_eid[clampi(pos,0,ECN-1)] = e;
    }
}

// wave-per-node bitonic sort of eid (deterministic order) + srcarr fill
__global__ __launch_bounds__(256) void k_sortfill(const int* __restrict__ c_src){
    const int wv = threadIdx.x >> 6, lane = threadIdx.x & 63;
    const int d = blockIdx.x*4 + wv;
    int b = clampi(g_off[d],0,ECN), e = clampi(g_off[d+1],b,ECN);
    int deg = e - b;
    if (deg <= 64){
        int v = (lane < deg) ? g_eid[b+lane] : 0x7fffffff;
        #pragma unroll
        for (int k=2;k<=64;k<<=1){
            #pragma unroll
            for (int j=k>>1;j>0;j>>=1){
                int p = __shfl_xor(v, j, 64);
                bool takeMin = ((lane & j)==0) == ((lane & k)==0);
                v = takeMin ? min(v,p) : max(v,p);
            }
        }
        if (lane < deg){
            g_eid[b+lane] = v;
            g_srcarr[b+lane] = clampi(c_src[clampi(v,0,ECN-1)],0,NCN-1);
        }
    } else if (lane == 0){
        for (int i=b+1;i<e;i++){
            int key = g_eid[i]; int j = i-1;
            while (j>=b && g_eid[j]>key){ g_eid[j+1]=g_eid[j]; j--; }
            g_eid[j+1] = key;
        }
        for (int i=b;i<e;i++) g_srcarr[i] = clampi(c_src[clampi(g_eid[i],0,ECN-1)],0,NCN-1);
    }
}

// edge-feature aggregates -> bf16 tails of g_hf / g_hf0 (+zero padding)
__global__ __launch_bounds__(256) void k_eagg(const float* __restrict__ ef){
    int d = blockIdx.x*16 + threadIdx.x/16;
    int f = threadIdx.x%16;
    if (d < NCN){
        float s=0.f, sr=0.f;
        int b=clampi(g_off[d],0,ECN), e=clampi(g_off[d+1],b,ECN);
        for (int i=b;i<e;i++){
            float v = ef[(size_t)clampi(g_eid[i],0,ECN-1)*CEE + f];
            s += v; sr += fmaxf(v,0.f);
        }
        g_hf [(size_t)d*HFB  + NHH + f]      = f2bu(s);
        g_hf [(size_t)d*HFB  + NHH + 16 + f] = 0;        // K pad 272..287
        g_hf0[(size_t)d*HFB0 + 72 + f]       = f2bu(sr);
        if (f < 8) g_hf0[(size_t)d*HFB0 + 88 + f] = 0;   // K pad 88..95
        if (f < 4) g_hf0[(size_t)d*HFB0 + 68 + f] = 0;   // 68..71 (v0 slot handled in f32 epilogue)
    }
}

// ---- topo helpers ----
__device__ __forceinline__ void topo_edges_norms(
    const int* __restrict__ t_src, const int* __restrict__ t_dst,
    int* ssrc, int* sdst, int* sdeg, float* onrm, float* inrm, int t)
{
    if (t < 2*NTT) sdeg[t]=0;
    __syncthreads();
    if (t < ETT){
        int s=clampi(t_src[t],0,NTT-1), d=clampi(t_dst[t],0,NTT-1);
        ssrc[t]=s; sdst[t]=d;
        atomicAdd(&sdeg[s],1); atomicAdd(&sdeg[NTT+d],1);
    }
    __syncthreads();
    if (t < NTT){
        onrm[t]=rsqrtf((float)max(sdeg[t],1));
        inrm[t]=rsqrtf((float)max(sdeg[NTT+t],1));
    }
    __syncthreads();
}

__global__ __launch_bounds__(256) void kt_l0(
    const float* __restrict__ tfeats, const float* __restrict__ tef,
    const float* __restrict__ tW0, const float* __restrict__ tb0,
    const int* __restrict__ t_src, const int* __restrict__ t_dst)
{
    __shared__ float h[48];
    __shared__ int ssrc[ETT], sdst[ETT], sdeg[2*NTT];
    __shared__ float onrm[NTT], inrm[NTT];
    const int d = blockIdx.x, t = threadIdx.x;
    topo_edges_norms(t_src, t_dst, ssrc, sdst, sdeg, onrm, inrm, t);
    if (t < 48){
        float acc=0.f;
        for (int e=0;e<ETT;e++){
            if (sdst[e]==d){
                int s=ssrc[e];
                float v = (t<TFF) ? tfeats[s*TFF+t]*onrm[s] : tef[e*TEE+(t-TFF)];
                acc += fmaxf(v,0.f);
            }
        }
        h[t]=acc;
    }
    __syncthreads();
    float acc=0.f;
    for (int k=0;k<48;k++) acc += h[k]*tW0[k*NHH+t];
    g_tx0[d*NHH+t] = fmaxf(acc*inrm[d]+tb0[t], 0.f);
}

template<int DIR>
__global__ __launch_bounds__(256) void kt_lr(
    const float* __restrict__ tef,
    const float* __restrict__ W, const float* __restrict__ bias,
    const int* __restrict__ t_src, const int* __restrict__ t_dst, int relu_res)
{
    const float* xin  = DIR ? g_tx1 : g_tx0;
    float*       xout = DIR ? g_tx0 : g_tx1;
    __shared__ float h[NHH+TEE];
    __shared__ int ssrc[ETT], sdst[ETT], sdeg[2*NTT];
    __shared__ float onrm[NTT], inrm[NTT];
    const int d = blockIdx.x, t = threadIdx.x;
    topo_edges_norms(t_src, t_dst, ssrc, sdst, sdeg, onrm, inrm, t);
    {
        float a0=0.f, a1=0.f;
        for (int e=0;e<ETT;e++){
            if (sdst[e]==d){
                a0 += xin[ssrc[e]*NHH+t]*onrm[ssrc[e]];
                if (t<TEE) a1 += tef[e*TEE+t];
            }
        }
        h[t]=a0;
        if (t<TEE) h[NHH+t]=a1;
    }
    __syncthreads();
    float acc=0.f;
    for (int k=0;k<NHH+TEE;k++) acc += h[k]*W[(size_t)k*NHH+t];
    float val = acc*inrm[d] + bias[t];
    xout[d*NHH+t] = relu_res ? (xin[d*NHH+t]*onrm[d] + fmaxf(val,0.f)) : val;
}

__global__ __launch_bounds__(256) void k_v0(const float* __restrict__ cW0, const int* __restrict__ tgroups){
    __shared__ float srt[NHH];
    int b=blockIdx.x, c=threadIdx.x;
    int i0=clampi(tgroups[b*2+0],0,NTT-1), i1=clampi(tgroups[b*2+1],0,NTT-1);
    srt[c]=fmaxf(g_tx1[i0*NHH+c]+g_tx1[i1*NHH+c],0.f);
    __syncthreads();
    const float* Wm = cW0 + (size_t)(CFF+OPEE + b*NHH)*NHH;
    float acc=0.f;
    for (int j=0;j<NHH;j++) acc += srt[j]*Wm[(size_t)j*NHH+c];
    g_v0p[b*NHH+c]=acc;
}
__global__ __launch_bounds__(256) void k_v0r(){
    int c=threadIdx.x;
    float s=0.f;
    for (int b=0;b<TGG;b++) s+=g_v0p[b*NHH+c];
    g_v0[c]=s;
}

// ---------------- layer-0 gather: one wave per node, bf16 hf0 + f32 s_on ----------------
__global__ __launch_bounds__(256) void k_gather0(
    const int* __restrict__ ctypes,
    const float* __restrict__ cfeats, const float* __restrict__ opemb)
{
    const int wv = threadIdx.x >> 6, lane = threadIdx.x & 63;
    const int d = blockIdx.x*4 + wv;
    int b = g_off[d], e = g_off[d+1];
    float a_cf=0.f, a_op=0.f, aon=0.f;
    for (int i=b;i<e;i++){
        int s = g_srcarr[i];
        float on = g_onorm[s];
        a_cf += fmaxf(cfeats[(size_t)s*CFF+lane],0.f)*on;
        if (lane < OPEE){
            int ct = clampi(ctypes[s],0,255);
            a_op += fmaxf(opemb[ct*OPEE+lane],0.f)*on;
        }
        aon += on;
    }
    ushort* row = g_hf0 + (size_t)d*HFB0;
    row[lane] = f2bu(a_cf);
    if (lane < OPEE)  row[CFF+lane] = f2bu(a_op);
    if (lane == 4)    g_son[d] = aon;
}

// ---------------- layer-0 MFMA GEMM: writes f32 xn0 + bf16 mirror ----------------
__global__ __launch_bounds__(256) void k_gemm0(const float* __restrict__ cb0){
    const int d0 = blockIdx.x*16;
    const int w = threadIdx.x>>6, l = threadIdx.x&63;
    const ushort* arow = g_hf0 + (size_t)(d0 + (l&15))*HFB0 + 8*(l>>4);
    f32x4 acc0={0,0,0,0}, acc1={0,0,0,0}, acc2={0,0,0,0}, acc3={0,0,0,0};
    for (int kt=0; kt<3; kt++){
        bf16x8 a = *(const bf16x8*)(arow + kt*32);
        const ushort* bp = g_wpk0 + ((size_t)((kt*16 + w*4)*64 + l))*8;
        bf16x8 b0 = *(const bf16x8*)(bp);
        bf16x8 b1 = *(const bf16x8*)(bp + 64*8);
        bf16x8 b2 = *(const bf16x8*)(bp + 2*64*8);
        bf16x8 b3 = *(const bf16x8*)(bp + 3*64*8);
        acc0 = __builtin_amdgcn_mfma_f32_16x16x32_bf16(a, b0, acc0, 0,0,0);
        acc1 = __builtin_amdgcn_mfma_f32_16x16x32_bf16(a, b1, acc1, 0,0,0);
        acc2 = __builtin_amdgcn_mfma_f32_16x16x32_bf16(a, b2, acc2, 0,0,0);
        acc3 = __builtin_amdgcn_mfma_f32_16x16x32_bf16(a, b3, acc3, 0,0,0);
    }
    const int rb = (l>>4)*4, cb = w*64 + (l&15);
    #define EPI0(ACC, NT) { \
        int col = cb + (NT)*16; float bb = cb0[col]; float v0c = g_v0[col]; \
        _Pragma("unroll") for (int r=0;r<4;r++){ \
            int d = d0 + rb + r; \
            float val = (ACC[r] + g_son[d]*v0c)*g_inorm[d] + bb; \
            float xn = fmaxf(val,0.f)*g_onorm[d]; \
            g_x0 [(size_t)d*NHH+col] = xn; \
            g_xb0[(size_t)d*NHH+col] = f2bu(xn); } }
    EPI0(acc0,0) EPI0(acc1,1) EPI0(acc2,2) EPI0(acc3,3)
    #undef EPI0
}

// ---------------- recurrent gather: one wave per node, reads bf16 state ----------------
template<int DIR>   // DIR=0: read g_xb0, DIR=1: read g_xb1
__global__ __launch_bounds__(256) void k_gather(){
    const ushort* xb = DIR ? g_xb1 : g_xb0;
    const int wv = threadIdx.x >> 6, lane = threadIdx.x & 63;
    const int d = blockIdx.x*4 + wv;
    int b = g_off[d], e = g_off[d+1];
    float a0=0.f,a1=0.f,a2=0.f,a3=0.f;
    for (int i=b;i<e;i++){
        int s = g_srcarr[i];
        ushort4 v = *(const ushort4*)(xb + (size_t)s*NHH + 4*lane);
        a0 += bu2f(v.x); a1 += bu2f(v.y); a2 += bu2f(v.z); a3 += bu2f(v.w);
    }
    ushort4 o;
    o.x=f2bu(a0); o.y=f2bu(a1); o.z=f2bu(a2); o.w=f2bu(a3);
    *(ushort4*)(g_hf + (size_t)d*HFB + 4*lane) = o;   // [256:288] tail pre-baked by k_eagg
}

// ---------------- recurrent MFMA GEMM ----------------
template<int DIR>   // DIR=0: residual/in g_x0 -> out g_x1(+xb1); DIR=1: reverse
__global__ __launch_bounds__(256) void k_gemmr(
    int loff, const float* __restrict__ bias, int relu_res)
{
    const float* xnin = DIR ? g_x1 : g_x0;
    float*       xout = DIR ? g_x0 : g_x1;
    ushort*      xbout= DIR ? g_xb0 : g_xb1;
    const int d0 = blockIdx.x*16;
    const int w = threadIdx.x>>6, l = threadIdx.x&63;
    const ushort* arow = g_hf + (size_t)(d0 + (l&15))*HFB + 8*(l>>4);
    f32x4 acc0={0,0,0,0}, acc1={0,0,0,0}, acc2={0,0,0,0}, acc3={0,0,0,0};
    for (int kt=0; kt<9; kt++){
        bf16x8 a = *(const bf16x8*)(arow + kt*32);
        const ushort* bp = g_wpk + ((size_t)(((loff+kt)*16 + w*4)*64 + l))*8;
        bf16x8 b0 = *(const bf16x8*)(bp);
        bf16x8 b1 = *(const bf16x8*)(bp + 64*8);
        bf16x8 b2 = *(const bf16x8*)(bp + 2*64*8);
        bf16x8 b3 = *(const bf16x8*)(bp + 3*64*8);
        acc0 = __builtin_amdgcn_mfma_f32_16x16x32_bf16(a, b0, acc0, 0,0,0);
        acc1 = __builtin_amdgcn_mfma_f32_16x16x32_bf16(a, b1, acc1, 0,0,0);
        acc2 = __builtin_amdgcn_mfma_f32_16x16x32_bf16(a, b2, acc2, 0,0,0);
        acc3 = __builtin_amdgcn_mfma_f32_16x16x32_bf16(a, b3, acc3, 0,0,0);
    }
    const int rb = (l>>4)*4, cb = w*64 + (l&15);
    #define EPIR(ACC, NT) { \
        int col = cb + (NT)*16; float bb = bias[col]; \
        _Pragma("unroll") for (int r=0;r<4;r++){ \
            int d = d0 + rb + r; \
            float val = ACC[r]*g_inorm[d] + bb; \
            if (relu_res){ \
                float y = xnin[(size_t)d*NHH+col] + fmaxf(val,0.f); \
                float yn = y*g_onorm[d]; \
                xout [(size_t)d*NHH+col] = yn; \
                xbout[(size_t)d*NHH+col] = f2bu(yn); \
            } else { \
                xout[(size_t)d*NHH+col] = val; \
            } } }
    EPIR(acc0,0) EPIR(acc1,1) EPIR(acc2,2) EPIR(acc3,3)
    #undef EPIR
}

// ---------------- pooling (4 deterministic partials) + heads ----------------
__global__ __launch_bounds__(256) void k_cemb(const int* __restrict__ cgroups){
    int g=blockIdx.x>>2, p=blockIdx.x&3, c=threadIdx.x;
    float s=0.f;
    for (int i=p*25;i<p*25+25;i++){
        int idx=clampi(cgroups[g*GSZ+i],0,NCN-1);
        s += g_x1[(size_t)idx*NHH+c];
    }
    g_cembp[(size_t)(p*GCN+g)*NHH+c]=s;
}

__global__ __launch_bounds__(256) void k_heads(
    const float* __restrict__ sW, const float* __restrict__ sb,
    const float* __restrict__ nW, const float* __restrict__ nb, float* __restrict__ out)
{
    __shared__ float red[256];
    __shared__ float z[9];
    int g=blockIdx.x, t=threadIdx.x;
    float e = g_cembp[(size_t)(0*GCN+g)*NHH+t] + g_cembp[(size_t)(1*GCN+g)*NHH+t]
            + g_cembp[(size_t)(2*GCN+g)*NHH+t] + g_cembp[(size_t)(3*GCN+g)*NHH+t];
    for (int j=0;j<9;j++){
        float w = (j==0) ? nW[t] : sW[t*TGG+(j-1)];
        red[t]=e*w; __syncthreads();
        for (int s=128;s>0;s>>=1){ if (t<s) red[t]+=red[t+s]; __syncthreads(); }
        if (t==0) z[j]=red[0];
        __syncthreads();
    }
    if (t==0){
        float z0 = z[0] + nb[0];
        float lsig = fminf(z0,0.f) - log1pf(expf(-fabsf(z0)));
        out[g*9+0]=lsig;
        float zz[8]; float m=-1e30f;
        for (int j=0;j<8;j++){ zz[j]=z[j+1]+sb[j]; m=fmaxf(m,zz[j]); }
        float s=0.f;
        for (int j=0;j<8;j++) s+=expf(zz[j]-m);
        float lse=m+logf(s);
        for (int j=0;j<8;j++) out[g*9+1+j]=zz[j]-lse;
    }
}

extern "C" void kernel_launch(void* const* d_in, const int* in_sizes, int n_in,
                              void* d_out, int out_size, void* d_ws, size_t ws_size,
                              hipStream_t stream) {
    const int expect[24] = {
        NCN*CFF, ECN*CEE, NTT*TFF, ETT*TEE, 256*OPEE,
        (TFF+TEE)*NHH, NHH, 3*(NHH+TEE)*NHH, 3*NHH,
        (CFF+OPEE+TGG*NHH+CEE)*NHH, NHH, 5*(NHH+CEE)*NHH, 5*NHH,
        NHH*TGG, TGG, NHH, 1,
        NCN, ECN, ECN, ETT, ETT, GCN*GSZ, TGG*2
    };
    if (n_in < 24){
        k_badsize<<<(out_size+255)/256,256,0,stream>>>((float*)d_out, out_size, 2.0e6f);
        return;
    }
    for (int i=0;i<24;i++){
        if (in_sizes[i] != expect[i]){
            k_badsize<<<(out_size+255)/256,256,0,stream>>>((float*)d_out, out_size, 1.0e6f+(float)i);
            return;
        }
    }

    const float* cfeats = (const float*)d_in[0];
    const float* cef    = (const float*)d_in[1];
    const float* tfeats = (const float*)d_in[2];
    const float* tef    = (const float*)d_in[3];
    const float* opemb  = (const float*)d_in[4];
    const float* tW0    = (const float*)d_in[5];
    const float* tb0    = (const float*)d_in[6];
    const float* tWr    = (const float*)d_in[7];
    const float* tbr    = (const float*)d_in[8];
    const float* cW0    = (const float*)d_in[9];
    const float* cb0    = (const float*)d_in[10];
    const float* cWr    = (const float*)d_in[11];
    const float* cbr    = (const float*)d_in[12];
    const float* sW     = (const float*)d_in[13];
    const float* sb     = (const float*)d_in[14];
    const float* nW     = (const float*)d_in[15];
    const float* nb     = (const float*)d_in[16];
    const int* ctypes   = (const int*)d_in[17];
    const int* c_src    = (const int*)d_in[18];
    const int* c_dst    = (const int*)d_in[19];
    const int* t_src    = (const int*)d_in[20];
    const int* t_dst    = (const int*)d_in[21];
    const int* cgroups  = (const int*)d_in[22];
    const int* tgroups  = (const int*)d_in[23];

    const int EB = (ECN+255)/256, NB = (NCN+255)/256;

    k_packwr  <<<(5*9*16*64+255)/256, 256, 0, stream>>>(cWr);
    k_packw0  <<<(3*16*64+255)/256, 256, 0, stream>>>(cW0);

    k_zero3   <<<NB, 256, 0, stream>>>();
    k_degrees <<<EB, 256, 0, stream>>>(c_src, c_dst);
    k_norms   <<<NB, 256, 0, stream>>>();
    k_scan    <<<1, 1024, 0, stream>>>();
    k_scatter <<<EB, 256, 0, stream>>>(c_dst);
    k_sortfill<<<NCN/4, 256, 0, stream>>>(c_src);
    k_eagg    <<<(NCN+15)/16, 256, 0, stream>>>(cef);

    // topo GNN (f32, unchanged)
    kt_l0    <<<NTT, 256, 0, stream>>>(tfeats, tef, tW0, tb0, t_src, t_dst);
    kt_lr<0> <<<NTT, 256, 0, stream>>>(tef, tWr + (size_t)0*(NHH+TEE)*NHH, tbr + 0*NHH, t_src, t_dst, 1);
    kt_lr<1> <<<NTT, 256, 0, stream>>>(tef, tWr + (size_t)1*(NHH+TEE)*NHH, tbr + 1*NHH, t_src, t_dst, 1);
    kt_lr<0> <<<NTT, 256, 0, stream>>>(tef, tWr + (size_t)2*(NHH+TEE)*NHH, tbr + 2*NHH, t_src, t_dst, 0);
    k_v0     <<<TGG, 256, 0, stream>>>(cW0, tgroups);
    k_v0r    <<<1, 256, 0, stream>>>();

    // cGNN layer 0 (gather + MFMA GEMM), xn0 -> g_x0 (+bf16 mirror)
    k_gather0<<<NCN/4, 256, 0, stream>>>(ctypes, cfeats, opemb);
    k_gemm0  <<<NCN/16, 256, 0, stream>>>(cb0);

    // 5 recurrent layers: x0 -> x1 -> x0 -> x1 -> x0 -> x1 (final raw f32 in g_x1)
    k_gather<0><<<NCN/4, 256, 0, stream>>>();
    k_gemmr <0><<<NCN/16, 256, 0, stream>>>(0*9, cbr + 0*NHH, 1);
    k_gather<1><<<NCN/4, 256, 0, stream>>>();
    k_gemmr <1><<<NCN/16, 256, 0, stream>>>(1*9, cbr + 1*NHH, 1);
    k_gather<0><<<NCN/4, 256, 0, stream>>>();
    k_gemmr <0><<<NCN/16, 256, 0, stream>>>(2*9, cbr + 2*NHH, 1);
    k_gather<1><<<NCN/4, 256, 0, stream>>>();
    k_gemmr <1><<<NCN/16, 256, 0, stream>>>(3*9, cbr + 3*NHH, 1);
    k_gather<0><<<NCN/4, 256, 0, stream>>>();
    k_gemmr <0><<<NCN/16, 256, 0, stream>>>(4*9, cbr + 4*NHH, 0);

    k_cemb <<<4*GCN, 256, 0, stream>>>(cgroups);
    k_heads<<<GCN, 256, 0, stream>>>(sW, sb, nW, nb, (float*)d_out);
}

// Round 14
// 312.402 us; speedup vs baseline: 1.6452x; 1.0785x over previous
//
#include <hip/hip_runtime.h>
#include <hip/hip_bf16.h>

#define NCN 10000   // computation nodes
#define ECN 120000  // computation edges
#define NHH 256     // hidden
#define CEE 16      // cedge feat dim
#define GCN 100     // cgroups
#define GSZ 100     // nodes per cgroup
#define NTT 16      // topo nodes
#define ETT 64      // topo edges
#define TGG 8       // tgroups
#define OPEE 4
#define CFF 64
#define TFF 32
#define TEE 16
#define HFW 272     // true K (256 + 16 eagg)
#define HFB 288     // padded K for MFMA (9*32)
#define HFB0 96     // layer-0 padded K (3*32)
#define NPACKR (5*9*16*64)   // 46080 packwr items -> 180 blocks
#define NPACK0 (3*16*64)     // 3072 packw0 items  -> 12 blocks

typedef __attribute__((ext_vector_type(8))) short bf16x8;
typedef __attribute__((ext_vector_type(4))) float f32x4;

// ---------- static device scratch (no d_ws dependency) ----------
__device__ int    g_indeg[NCN];
__device__ int    g_outdeg[NCN];
__device__ int    g_cursor[NCN];
__device__ int    g_off[NCN+1];
__device__ int    g_eid[ECN];
__device__ int    g_srcarr[ECN];
__device__ float  g_onorm[NCN];
__device__ float  g_inorm[NCN];
__device__ float  g_son[NCN];
__device__ float  g_tx0[NTT*NHH];
__device__ float  g_tx1[NTT*NHH];
__device__ float  g_v0p[TGG*NHH];
__device__ float  g_v0[NHH];
__device__ float  g_x0[(size_t)NCN*NHH];     // f32 xn state (normalized) / final raw
__device__ float  g_x1[(size_t)NCN*NHH];
__device__ ushort g_xb0[(size_t)NCN*NHH];    // bf16 mirror of xn (gather input)
__device__ ushort g_xb1[(size_t)NCN*NHH];
__device__ ushort g_hf [(size_t)NCN*HFB];    // bf16 gathered rows; [256:272]=eagg, [272:288]=0
__device__ ushort g_hf0[(size_t)NCN*HFB0];   // bf16 layer-0 rows
__device__ ushort g_wpk [NPACKR*8];          // cWr packed into B-fragment order
__device__ ushort g_wpk0[NPACK0*8];          // cW0 packed (k=68..71 zeroed; v0 term in f32 epilogue)
__device__ float  g_cembp[4*GCN*NHH];

__device__ __forceinline__ int clampi(int v,int lo,int hi){ return v<lo?lo:(v>hi?hi:v); }
__device__ __forceinline__ ushort f2bu(float f){ __hip_bfloat16 h=__float2bfloat16(f); return *reinterpret_cast<ushort*>(&h); }
__device__ __forceinline__ float  bu2f(ushort u){ return __uint_as_float(((unsigned)u)<<16); }

__global__ __launch_bounds__(256) void k_badsize(float* out, int n, float code){
    int i = blockIdx.x*256 + threadIdx.x;
    if (i < n) out[i] = code;
}

// ---------------- prep0: packwr (blocks 0..179) | packw0 (180..191) | zero (192..231) ----------------
__global__ __launch_bounds__(256) void k_prep0(const float* __restrict__ cWr, const float* __restrict__ cW0){
    int bid = blockIdx.x, t = threadIdx.x;
    if (bid < 180){
        int i = bid*256 + t;                        // over NPACKR
        if (i >= NPACKR) return;
        int lane = i&63, u = i>>6;
        int ntg = u&15; u >>= 4;
        int kt = u%9, l = u/9;
        int col = ntg*16 + (lane&15);
        int kb = kt*32 + 8*(lane>>4);
        #pragma unroll
        for (int j=0;j<8;j++){
            int k = kb + j;
            float v = (k < HFW) ? cWr[(size_t)l*HFW*NHH + (size_t)k*NHH + col] : 0.f;
            g_wpk[(size_t)i*8 + j] = f2bu(v);
        }
    } else if (bid < 192){
        int i = (bid-180)*256 + t;                  // over NPACK0
        if (i >= NPACK0) return;
        int lane = i&63, u = i>>6;
        int ntg = u&15, kt = u>>4;
        int col = ntg*16 + (lane&15);
        int kb = kt*32 + 8*(lane>>4);
        #pragma unroll
        for (int j=0;j<8;j++){
            int k = kb + j;
            float v = 0.f;
            if (k < CFF+OPEE)            v = cW0[(size_t)k*NHH+col];
            else if (k >= 72 && k < 88)  v = cW0[(size_t)(CFF+OPEE+TGG*NHH + (k-72))*NHH + col];
            g_wpk0[(size_t)i*8 + j] = f2bu(v);
        }
    } else {
        int i = (bid-192)*256 + t;
        if (i < NCN){ g_indeg[i]=0; g_outdeg[i]=0; g_cursor[i]=0; }
    }
}

// ---------------- graph prep ----------------
__global__ __launch_bounds__(256) void k_degrees(const int* __restrict__ src, const int* __restrict__ dst){
    int e = blockIdx.x*256 + threadIdx.x;
    if (e < ECN){
        atomicAdd(&g_outdeg[clampi(src[e],0,NCN-1)],1);
        atomicAdd(&g_indeg [clampi(dst[e],0,NCN-1)],1);
    }
}

// exclusive scan of indeg -> off[0..NCN]; also degree norms (fused)
__global__ __launch_bounds__(1024) void k_scan(){
    __shared__ int cs[1024];
    const int CH = (NCN + 1023)/1024;
    int t = threadIdx.x;
    int base = t*CH;
    for (int j=0;j<CH;j++){
        int idx = base+j;
        if (idx < NCN){
            g_onorm[idx] = rsqrtf((float)max(g_outdeg[idx],1));
            g_inorm[idx] = rsqrtf((float)max(g_indeg[idx],1));
        }
    }
    int s = 0;
    for (int j=0;j<CH;j++){ int idx=base+j; if (idx<NCN) s += g_indeg[idx]; }
    cs[t] = s; __syncthreads();
    for (int ofs=1; ofs<1024; ofs<<=1){
        int v = (t>=ofs) ? cs[t-ofs] : 0;
        __syncthreads();
        cs[t] += v;
        __syncthreads();
    }
    int run = (t==0) ? 0 : cs[t-1];
    for (int j=0;j<CH;j++){
        int idx = base+j;
        if (idx <= NCN) g_off[idx] = run;
        if (idx < NCN) run += g_indeg[idx];
    }
}

__global__ __launch_bounds__(256) void k_scatter(const int* __restrict__ dst){
    int e = blockIdx.x*256 + threadIdx.x;
    if (e < ECN){
        int d = clampi(dst[e],0,NCN-1);
        int pos = g_off[d] + atomicAdd(&g_cursor[d],1);
        g_eid[clampi(pos,0,ECN-1)] = e;
    }
}

// wave-per-node bitonic sort of eid + srcarr fill + fused edge-feature aggregation
__global__ __launch_bounds__(256) void k_sortfill(const int* __restrict__ c_src, const float* __restrict__ ef){
    const int wv = threadIdx.x >> 6, lane = threadIdx.x & 63;
    const int d = blockIdx.x*4 + wv;
    int b = clampi(g_off[d],0,ECN), e = clampi(g_off[d+1],b,ECN);
    int deg = e - b;
    if (deg <= 64){
        int v = (lane < deg) ? g_eid[b+lane] : 0x7fffffff;
        #pragma unroll
        for (int k=2;k<=64;k<<=1){
            #pragma unroll
            for (int j=k>>1;j>0;j>>=1){
                int p = __shfl_xor(v, j, 64);
                bool takeMin = ((lane & j)==0) == ((lane & k)==0);
                v = takeMin ? min(v,p) : max(v,p);
            }
        }
        if (lane < deg){
            g_eid[b+lane] = v;
            g_srcarr[b+lane] = clampi(c_src[clampi(v,0,ECN-1)],0,NCN-1);
        }
        // fused eagg: sorted eids live in registers; shfl them
        float s=0.f, sr=0.f;
        for (int i=0;i<deg;i++){
            int ei = __shfl(v, i&63);
            if (lane < CEE){
                float val = ef[(size_t)clampi(ei,0,ECN-1)*CEE + lane];
                s += val; sr += fmaxf(val,0.f);
            }
        }
        if (lane < CEE){
            g_hf [(size_t)d*HFB  + NHH + lane]      = f2bu(s);
            g_hf [(size_t)d*HFB  + NHH + 16 + lane] = 0;
            g_hf0[(size_t)d*HFB0 + 72 + lane]       = f2bu(sr);
            if (lane < 8) g_hf0[(size_t)d*HFB0 + 88 + lane] = 0;
            if (lane < 4) g_hf0[(size_t)d*HFB0 + 68 + lane] = 0;
        }
    } else if (lane == 0){
        for (int i=b+1;i<e;i++){
            int key = g_eid[i]; int j = i-1;
            while (j>=b && g_eid[j]>key){ g_eid[j+1]=g_eid[j]; j--; }
            g_eid[j+1] = key;
        }
        for (int i=b;i<e;i++) g_srcarr[i] = clampi(c_src[clampi(g_eid[i],0,ECN-1)],0,NCN-1);
        for (int f=0;f<CEE;f++){
            float s=0.f, sr=0.f;
            for (int i=b;i<e;i++){
                float val = ef[(size_t)clampi(g_eid[i],0,ECN-1)*CEE + f];
                s += val; sr += fmaxf(val,0.f);
            }
            g_hf [(size_t)d*HFB  + NHH + f]      = f2bu(s);
            g_hf [(size_t)d*HFB  + NHH + 16 + f] = 0;
            g_hf0[(size_t)d*HFB0 + 72 + f]       = f2bu(sr);
            if (f < 8) g_hf0[(size_t)d*HFB0 + 88 + f] = 0;
            if (f < 4) g_hf0[(size_t)d*HFB0 + 68 + f] = 0;
        }
    }
}

// ---- topo helpers ----
__device__ __forceinline__ void topo_edges_norms(
    const int* __restrict__ t_src, const int* __restrict__ t_dst,
    int* ssrc, int* sdst, int* sdeg, float* onrm, float* inrm, int t)
{
    if (t < 2*NTT) sdeg[t]=0;
    __syncthreads();
    if (t < ETT){
        int s=clampi(t_src[t],0,NTT-1), d=clampi(t_dst[t],0,NTT-1);
        ssrc[t]=s; sdst[t]=d;
        atomicAdd(&sdeg[s],1); atomicAdd(&sdeg[NTT+d],1);
    }
    __syncthreads();
    if (t < NTT){
        onrm[t]=rsqrtf((float)max(sdeg[t],1));
        inrm[t]=rsqrtf((float)max(sdeg[NTT+t],1));
    }
    __syncthreads();
}

__global__ __launch_bounds__(256) void kt_l0(
    const float* __restrict__ tfeats, const float* __restrict__ tef,
    const float* __restrict__ tW0, const float* __restrict__ tb0,
    const int* __restrict__ t_src, const int* __restrict__ t_dst)
{
    __shared__ float h[48];
    __shared__ int ssrc[ETT], sdst[ETT], sdeg[2*NTT];
    __shared__ float onrm[NTT], inrm[NTT];
    const int d = blockIdx.x, t = threadIdx.x;
    topo_edges_norms(t_src, t_dst, ssrc, sdst, sdeg, onrm, inrm, t);
    if (t < 48){
        float acc=0.f;
        for (int e=0;e<ETT;e++){
            if (sdst[e]==d){
                int s=ssrc[e];
                float v = (t<TFF) ? tfeats[s*TFF+t]*onrm[s] : tef[e*TEE+(t-TFF)];
                acc += fmaxf(v,0.f);
            }
        }
        h[t]=acc;
    }
    __syncthreads();
    float acc=0.f;
    for (int k=0;k<48;k++) acc += h[k]*tW0[k*NHH+t];
    g_tx0[d*NHH+t] = fmaxf(acc*inrm[d]+tb0[t], 0.f);
}

template<int DIR>
__global__ __launch_bounds__(256) void kt_lr(
    const float* __restrict__ tef,
    const float* __restrict__ W, const float* __restrict__ bias,
    const int* __restrict__ t_src, const int* __restrict__ t_dst, int relu_res)
{
    const float* xin  = DIR ? g_tx1 : g_tx0;
    float*       xout = DIR ? g_tx0 : g_tx1;
    __shared__ float h[NHH+TEE];
    __shared__ int ssrc[ETT], sdst[ETT], sdeg[2*NTT];
    __shared__ float onrm[NTT], inrm[NTT];
    const int d = blockIdx.x, t = threadIdx.x;
    topo_edges_norms(t_src, t_dst, ssrc, sdst, sdeg, onrm, inrm, t);
    {
        float a0=0.f, a1=0.f;
        for (int e=0;e<ETT;e++){
            if (sdst[e]==d){
                a0 += xin[ssrc[e]*NHH+t]*onrm[ssrc[e]];
                if (t<TEE) a1 += tef[e*TEE+t];
            }
        }
        h[t]=a0;
        if (t<TEE) h[NHH+t]=a1;
    }
    __syncthreads();
    float acc=0.f;
    for (int k=0;k<NHH+TEE;k++) acc += h[k]*W[(size_t)k*NHH+t];
    float val = acc*inrm[d] + bias[t];
    xout[d*NHH+t] = relu_res ? (xin[d*NHH+t]*onrm[d] + fmaxf(val,0.f)) : val;
}

__global__ __launch_bounds__(256) void k_v0(const float* __restrict__ cW0, const int* __restrict__ tgroups){
    __shared__ float srt[NHH];
    int b=blockIdx.x, c=threadIdx.x;
    int i0=clampi(tgroups[b*2+0],0,NTT-1), i1=clampi(tgroups[b*2+1],0,NTT-1);
    srt[c]=fmaxf(g_tx1[i0*NHH+c]+g_tx1[i1*NHH+c],0.f);
    __syncthreads();
    const float* Wm = cW0 + (size_t)(CFF+OPEE + b*NHH)*NHH;
    float acc=0.f;
    for (int j=0;j<NHH;j++) acc += srt[j]*Wm[(size_t)j*NHH+c];
    g_v0p[b*NHH+c]=acc;
}
__global__ __launch_bounds__(256) void k_v0r(){
    int c=threadIdx.x;
    float s=0.f;
    for (int b=0;b<TGG;b++) s+=g_v0p[b*NHH+c];
    g_v0[c]=s;
}

// ---------------- layer-0 gather: one wave per node, shfl-resident edge scalars ----------------
__global__ __launch_bounds__(256) void k_gather0(
    const int* __restrict__ ctypes,
    const float* __restrict__ cfeats, const float* __restrict__ opemb)
{
    const int wv = threadIdx.x >> 6, lane = threadIdx.x & 63;
    const int d = blockIdx.x*4 + wv;
    int b = g_off[d], e = g_off[d+1];
    int deg = e - b;
    int sv = 0; float onv = 0.f; int ctv = 0;
    if (lane < deg){
        int s = g_srcarr[b+lane];
        sv = s; onv = g_onorm[s]; ctv = clampi(ctypes[s],0,255);
    }
    float a_cf=0.f, a_op=0.f, aon=0.f;
    for (int i=0;i<deg;i++){
        int s; float on; int ct;
        if (i < 64){ s = __shfl(sv,i&63); on = __shfl(onv,i&63); ct = __shfl(ctv,i&63); }
        else { s = g_srcarr[b+i]; on = g_onorm[s]; ct = clampi(ctypes[s],0,255); }
        a_cf += fmaxf(cfeats[(size_t)s*CFF+lane],0.f)*on;
        if (lane < OPEE) a_op += fmaxf(opemb[ct*OPEE+lane],0.f)*on;
        aon += on;
    }
    ushort* row = g_hf0 + (size_t)d*HFB0;
    row[lane] = f2bu(a_cf);
    if (lane < OPEE)  row[CFF+lane] = f2bu(a_op);
    if (lane == 4)    g_son[d] = aon;
}

// ---------------- layer-0 MFMA GEMM: writes f32 xn0 + bf16 mirror ----------------
__global__ __launch_bounds__(256) void k_gemm0(const float* __restrict__ cb0){
    const int d0 = blockIdx.x*16;
    const int w = threadIdx.x>>6, l = threadIdx.x&63;
    const ushort* arow = g_hf0 + (size_t)(d0 + (l&15))*HFB0 + 8*(l>>4);
    f32x4 acc0={0,0,0,0}, acc1={0,0,0,0}, acc2={0,0,0,0}, acc3={0,0,0,0};
    for (int kt=0; kt<3; kt++){
        bf16x8 a = *(const bf16x8*)(arow + kt*32);
        const ushort* bp = g_wpk0 + ((size_t)((kt*16 + w*4)*64 + l))*8;
        bf16x8 b0 = *(const bf16x8*)(bp);
        bf16x8 b1 = *(const bf16x8*)(bp + 64*8);
        bf16x8 b2 = *(const bf16x8*)(bp + 2*64*8);
        bf16x8 b3 = *(const bf16x8*)(bp + 3*64*8);
        acc0 = __builtin_amdgcn_mfma_f32_16x16x32_bf16(a, b0, acc0, 0,0,0);
        acc1 = __builtin_amdgcn_mfma_f32_16x16x32_bf16(a, b1, acc1, 0,0,0);
        acc2 = __builtin_amdgcn_mfma_f32_16x16x32_bf16(a, b2, acc2, 0,0,0);
        acc3 = __builtin_amdgcn_mfma_f32_16x16x32_bf16(a, b3, acc3, 0,0,0);
    }
    const int rb = (l>>4)*4, cb = w*64 + (l&15);
    #define EPI0(ACC, NT) { \
        int col = cb + (NT)*16; float bb = cb0[col]; float v0c = g_v0[col]; \
        _Pragma("unroll") for (int r=0;r<4;r++){ \
            int d = d0 + rb + r; \
            float val = (ACC[r] + g_son[d]*v0c)*g_inorm[d] + bb; \
            float xn = fmaxf(val,0.f)*g_onorm[d]; \
            g_x0 [(size_t)d*NHH+col] = xn; \
            g_xb0[(size_t)d*NHH+col] = f2bu(xn); } }
    EPI0(acc0,0) EPI0(acc1,1) EPI0(acc2,2) EPI0(acc3,3)
    #undef EPI0
}

// ---------------- recurrent gather: one wave per node, shfl-resident sources ----------------
template<int DIR>   // DIR=0: read g_xb0, DIR=1: read g_xb1
__global__ __launch_bounds__(256) void k_gather(){
    const ushort* xb = DIR ? g_xb1 : g_xb0;
    const int wv = threadIdx.x >> 6, lane = threadIdx.x & 63;
    const int d = blockIdx.x*4 + wv;
    int b = g_off[d], e = g_off[d+1];
    int deg = e - b;
    int sv = (lane < deg) ? g_srcarr[b+lane] : 0;
    float a0=0.f,a1=0.f,a2=0.f,a3=0.f;
    for (int i=0;i<deg;i++){
        int s = (i < 64) ? __shfl(sv,i&63) : g_srcarr[b+i];
        ushort4 v = *(const ushort4*)(xb + (size_t)s*NHH + 4*lane);
        a0 += bu2f(v.x); a1 += bu2f(v.y); a2 += bu2f(v.z); a3 += bu2f(v.w);
    }
    ushort4 o;
    o.x=f2bu(a0); o.y=f2bu(a1); o.z=f2bu(a2); o.w=f2bu(a3);
    *(ushort4*)(g_hf + (size_t)d*HFB + 4*lane) = o;   // [256:288] tail pre-baked by k_sortfill
}

// ---------------- recurrent MFMA GEMM ----------------
template<int DIR>   // DIR=0: residual/in g_x0 -> out g_x1(+xb1); DIR=1: reverse
__global__ __launch_bounds__(256) void k_gemmr(
    int loff, const float* __restrict__ bias, int relu_res)
{
    const float* xnin = DIR ? g_x1 : g_x0;
    float*       xout = DIR ? g_x0 : g_x1;
    ushort*      xbout= DIR ? g_xb0 : g_xb1;
    const int d0 = blockIdx.x*16;
    const int w = threadIdx.x>>6, l = threadIdx.x&63;
    const ushort* arow = g_hf + (size_t)(d0 + (l&15))*HFB + 8*(l>>4);
    f32x4 acc0={0,0,0,0}, acc1={0,0,0,0}, acc2={0,0,0,0}, acc3={0,0,0,0};
    for (int kt=0; kt<9; kt++){
        bf16x8 a = *(const bf16x8*)(arow + kt*32);
        const ushort* bp = g_wpk + ((size_t)(((loff+kt)*16 + w*4)*64 + l))*8;
        bf16x8 b0 = *(const bf16x8*)(bp);
        bf16x8 b1 = *(const bf16x8*)(bp + 64*8);
        bf16x8 b2 = *(const bf16x8*)(bp + 2*64*8);
        bf16x8 b3 = *(const bf16x8*)(bp + 3*64*8);
        acc0 = __builtin_amdgcn_mfma_f32_16x16x32_bf16(a, b0, acc0, 0,0,0);
        acc1 = __builtin_amdgcn_mfma_f32_16x16x32_bf16(a, b1, acc1, 0,0,0);
        acc2 = __builtin_amdgcn_mfma_f32_16x16x32_bf16(a, b2, acc2, 0,0,0);
        acc3 = __builtin_amdgcn_mfma_f32_16x16x32_bf16(a, b3, acc3, 0,0,0);
    }
    const int rb = (l>>4)*4, cb = w*64 + (l&15);
    #define EPIR(ACC, NT) { \
        int col = cb + (NT)*16; float bb = bias[col]; \
        _Pragma("unroll") for (int r=0;r<4;r++){ \
            int d = d0 + rb + r; \
            float val = ACC[r]*g_inorm[d] + bb; \
            if (relu_res){ \
                float y = xnin[(size_t)d*NHH+col] + fmaxf(val,0.f); \
                float yn = y*g_onorm[d]; \
                xout [(size_t)d*NHH+col] = yn; \
                xbout[(size_t)d*NHH+col] = f2bu(yn); \
            } else { \
                xout[(size_t)d*NHH+col] = val; \
            } } }
    EPIR(acc0,0) EPIR(acc1,1) EPIR(acc2,2) EPIR(acc3,3)
    #undef EPIR
}

// ---------------- pooling (4 deterministic partials) + heads ----------------
__global__ __launch_bounds__(256) void k_cemb(const int* __restrict__ cgroups){
    int g=blockIdx.x>>2, p=blockIdx.x&3, c=threadIdx.x;
    float s=0.f;
    for (int i=p*25;i<p*25+25;i++){
        int idx=clampi(cgroups[g*GSZ+i],0,NCN-1);
        s += g_x1[(size_t)idx*NHH+c];
    }
    g_cembp[(size_t)(p*GCN+g)*NHH+c]=s;
}

__global__ __launch_bounds__(256) void k_heads(
    const float* __restrict__ sW, const float* __restrict__ sb,
    const float* __restrict__ nW, const float* __restrict__ nb, float* __restrict__ out)
{
    __shared__ float red[256];
    __shared__ float z[9];
    int g=blockIdx.x, t=threadIdx.x;
    float e = g_cembp[(size_t)(0*GCN+g)*NHH+t] + g_cembp[(size_t)(1*GCN+g)*NHH+t]
            + g_cembp[(size_t)(2*GCN+g)*NHH+t] + g_cembp[(size_t)(3*GCN+g)*NHH+t];
    for (int j=0;j<9;j++){
        float w = (j==0) ? nW[t] : sW[t*TGG+(j-1)];
        red[t]=e*w; __syncthreads();
        for (int s=128;s>0;s>>=1){ if (t<s) red[t]+=red[t+s]; __syncthreads(); }
        if (t==0) z[j]=red[0];
        __syncthreads();
    }
    if (t==0){
        float z0 = z[0] + nb[0];
        float lsig = fminf(z0,0.f) - log1pf(expf(-fabsf(z0)));
        out[g*9+0]=lsig;
        float zz[8]; float m=-1e30f;
        for (int j=0;j<8;j++){ zz[j]=z[j+1]+sb[j]; m=fmaxf(m,zz[j]); }
        float s=0.f;
        for (int j=0;j<8;j++) s+=expf(zz[j]-m);
        float lse=m+logf(s);
        for (int j=0;j<8;j++) out[g*9+1+j]=zz[j]-lse;
    }
}

extern "C" void kernel_launch(void* const* d_in, const int* in_sizes, int n_in,
                              void* d_out, int out_size, void* d_ws, size_t ws_size,
                              hipStream_t stream) {
    const int expect[24] = {
        NCN*CFF, ECN*CEE, NTT*TFF, ETT*TEE, 256*OPEE,
        (TFF+TEE)*NHH, NHH, 3*(NHH+TEE)*NHH, 3*NHH,
        (CFF+OPEE+TGG*NHH+CEE)*NHH, NHH, 5*(NHH+CEE)*NHH, 5*NHH,
        NHH*TGG, TGG, NHH, 1,
        NCN, ECN, ECN, ETT, ETT, GCN*GSZ, TGG*2
    };
    if (n_in < 24){
        k_badsize<<<(out_size+255)/256,256,0,stream>>>((float*)d_out, out_size, 2.0e6f);
        return;
    }
    for (int i=0;i<24;i++){
        if (in_sizes[i] != expect[i]){
            k_badsize<<<(out_size+255)/256,256,0,stream>>>((float*)d_out, out_size, 1.0e6f+(float)i);
            return;
        }
    }

    const float* cfeats = (const float*)d_in[0];
    const float* cef    = (const float*)d_in[1];
    const float* tfeats = (const float*)d_in[2];
    const float* tef    = (const float*)d_in[3];
    const float* opemb  = (const float*)d_in[4];
    const float* tW0    = (const float*)d_in[5];
    const float* tb0    = (const float*)d_in[6];
    const float* tWr    = (const float*)d_in[7];
    const float* tbr    = (const float*)d_in[8];
    const float* cW0    = (const float*)d_in[9];
    const float* cb0    = (const float*)d_in[10];
    const float* cWr    = (const float*)d_in[11];
    const float* cbr    = (const float*)d_in[12];
    const float* sW     = (const float*)d_in[13];
    const float* sb     = (const float*)d_in[14];
    const float* nW     = (const float*)d_in[15];
    const float* nb     = (const float*)d_in[16];
    const int* ctypes   = (const int*)d_in[17];
    const int* c_src    = (const int*)d_in[18];
    const int* c_dst    = (const int*)d_in[19];
    const int* t_src    = (const int*)d_in[20];
    const int* t_dst    = (const int*)d_in[21];
    const int* cgroups  = (const int*)d_in[22];
    const int* tgroups  = (const int*)d_in[23];

    const int EB = (ECN+255)/256;

    k_prep0   <<<232, 256, 0, stream>>>(cWr, cW0);
    k_degrees <<<EB, 256, 0, stream>>>(c_src, c_dst);
    k_scan    <<<1, 1024, 0, stream>>>();
    k_scatter <<<EB, 256, 0, stream>>>(c_dst);
    k_sortfill<<<NCN/4, 256, 0, stream>>>(c_src, cef);

    // topo GNN (f32)
    kt_l0    <<<NTT, 256, 0, stream>>>(tfeats, tef, tW0, tb0, t_src, t_dst);
    kt_lr<0> <<<NTT, 256, 0, stream>>>(tef, tWr + (size_t)0*(NHH+TEE)*NHH, tbr + 0*NHH, t_src, t_dst, 1);
    kt_lr<1> <<<NTT, 256, 0, stream>>>(tef, tWr + (size_t)1*(NHH+TEE)*NHH, tbr + 1*NHH, t_src, t_dst, 1);
    kt_lr<0> <<<NTT, 256, 0, stream>>>(tef, tWr + (size_t)2*(NHH+TEE)*NHH, tbr + 2*NHH, t_src, t_dst, 0);
    k_v0     <<<TGG, 256, 0, stream>>>(cW0, tgroups);
    k_v0r    <<<1, 256, 0, stream>>>();

    // cGNN layer 0
    k_gather0<<<NCN/4, 256, 0, stream>>>(ctypes, cfeats, opemb);
    k_gemm0  <<<NCN/16, 256, 0, stream>>>(cb0);

    // 5 recurrent layers: x0 -> x1 -> x0 -> x1 -> x0 -> x1 (final raw f32 in g_x1)
    k_gather<0><<<NCN/4, 256, 0, stream>>>();
    k_gemmr <0><<<NCN/16, 256, 0, stream>>>(0*9, cbr + 0*NHH, 1);
    k_gather<1><<<NCN/4, 256, 0, stream>>>();
    k_gemmr <1><<<NCN/16, 256, 0, stream>>>(1*9, cbr + 1*NHH, 1);
    k_gather<0><<<NCN/4, 256, 0, stream>>>();
    k_gemmr <0><<<NCN/16, 256, 0, stream>>>(2*9, cbr + 2*NHH, 1);
    k_gather<1><<<NCN/4, 256, 0, stream>>>();
    k_gemmr <1><<<NCN/16, 256, 0, stream>>>(3*9, cbr + 3*NHH, 1);
    k_gather<0><<<NCN/4, 256, 0, stream>>>();
    k_gemmr <0><<<NCN/16, 256, 0, stream>>>(4*9, cbr + 4*NHH, 0);

    k_cemb <<<4*GCN, 256, 0, stream>>>(cgroups);
    k_heads<<<GCN, 256, 0, stream>>>(sW, sb, nW, nb, (float*)d_out);
}